// Round 2
// baseline (1059.705 us; speedup 1.0000x reference)
//
#include <hip/hip_runtime.h>
#include <hip/hip_bf16.h>
#include <stdint.h>

typedef __attribute__((ext_vector_type(8))) short s16x8;
typedef __attribute__((ext_vector_type(4))) float f32x4;

static constexpr int Bb = 8, Ss = 2048, Ee = 1024, Ff = 4096;
static constexpr int M_TOK = Bb * Ss;                      // 16384
static constexpr size_t OUT_SLOT = (size_t)M_TOK * Ee;     // elements per output tensor

__device__ inline unsigned short f2bf(float f) {
  unsigned int u = __float_as_uint(f);
  unsigned int r = (u + 0x7FFFu + ((u >> 16) & 1u)) >> 16;
  return (unsigned short)r;
}
__device__ inline float bf2f(unsigned short h) {
  return __uint_as_float(((unsigned int)h) << 16);
}

// ---------------- elementwise f32 -> bf16 ----------------
__global__ __launch_bounds__(256) void k_cvt_f32_bf16(const float* __restrict__ in,
                                                      unsigned short* __restrict__ out, int n4) {
  int i = blockIdx.x * blockDim.x + threadIdx.x;
  int stride = gridDim.x * blockDim.x;
  for (; i < n4; i += stride) {
    float4 v = ((const float4*)in)[i];
    ushort4 o;
    o.x = f2bf(v.x); o.y = f2bf(v.y); o.z = f2bf(v.z); o.w = f2bf(v.w);
    ((ushort4*)out)[i] = o;
  }
}

// ---------------- transpose+convert W[R][C] f32 -> WT[C][R] bf16 ----------------
__global__ __launch_bounds__(256) void k_transpose_w(const float* __restrict__ in,
                                                     unsigned short* __restrict__ out,
                                                     int R, int C) {
  __shared__ float t[32][33];
  int c0 = blockIdx.x * 32, r0 = blockIdx.y * 32;
  int tx = threadIdx.x, ty = threadIdx.y;
  for (int i = ty; i < 32; i += 8)
    t[i][tx] = in[(size_t)(r0 + i) * C + c0 + tx];
  __syncthreads();
  for (int i = ty; i < 32; i += 8)
    out[(size_t)(c0 + i) * R + r0 + tx] = f2bf(t[tx][i]);
}

// ---------------- per-batch transpose v[S][E] bf16 -> vT[E][S] bf16 ----------------
__global__ __launch_bounds__(256) void k_transpose_v(const unsigned short* __restrict__ v,
                                                     unsigned short* __restrict__ vT) {
  __shared__ unsigned short t[32][33];
  int b = blockIdx.z;
  const unsigned short* in = v + (size_t)b * Ss * Ee;
  unsigned short* out = vT + (size_t)b * Ee * Ss;
  int c0 = blockIdx.x * 32, r0 = blockIdx.y * 32;  // c over E, r over S
  int tx = threadIdx.x, ty = threadIdx.y;
  for (int i = ty; i < 32; i += 8)
    t[i][tx] = in[(size_t)(r0 + i) * Ee + c0 + tx];
  __syncthreads();
  for (int i = ty; i < 32; i += 8)
    out[(size_t)(c0 + i) * Ss + r0 + tx] = t[tx][i];
}

// ---------------- bf16 GEMM: C = A[M,K] @ Bt[N,K]^T * scale (+bias) (+relu) ----------------
// 128x128 tile, BK=32, 4 waves (2x2), each wave 64x64 via 4x4 mfma_f32_16x16x32_bf16 frags.
// Dual output: f32 to Cf (d_out) and/or bf16 to Cb (workspace).
template <bool WF32, bool WB16, bool RELU, bool HAS_BIAS>
__global__ __launch_bounds__(256) void k_gemm_bt(const unsigned short* __restrict__ A,
                                                 const unsigned short* __restrict__ Bt,
                                                 float* __restrict__ Cf,
                                                 unsigned short* __restrict__ Cb,
                                                 const float* __restrict__ bias,
                                                 int M, int N, int K,
                                                 long aBatch, long bBatch, long cBatch,
                                                 float scale) {
  __shared__ unsigned short As[128][40];  // +8 pad -> 80B stride
  __shared__ unsigned short Bs[128][40];
  const int tid = threadIdx.x;
  const int lane = tid & 63;
  const int wid = tid >> 6;
  const int wm = (wid >> 1) * 64, wn = (wid & 1) * 64;
  const int m0 = blockIdx.x * 128, n0 = blockIdx.y * 128;
  const int z = blockIdx.z;
  A += (size_t)z * aBatch;
  Bt += (size_t)z * bBatch;

  f32x4 acc[4][4] = {};
  const int r0 = tid >> 2;
  const int c0 = (tid & 3) << 3;
  const int r1 = (tid + 256) >> 2;
  const int c1 = ((tid + 256) & 3) << 3;

  for (int k0 = 0; k0 < K; k0 += 32) {
    *(s16x8*)&As[r0][c0] = *(const s16x8*)(A + (size_t)(m0 + r0) * K + k0 + c0);
    *(s16x8*)&As[r1][c1] = *(const s16x8*)(A + (size_t)(m0 + r1) * K + k0 + c1);
    *(s16x8*)&Bs[r0][c0] = *(const s16x8*)(Bt + (size_t)(n0 + r0) * K + k0 + c0);
    *(s16x8*)&Bs[r1][c1] = *(const s16x8*)(Bt + (size_t)(n0 + r1) * K + k0 + c1);
    __syncthreads();
    const int fr = lane & 15, fk = (lane >> 4) << 3;
    s16x8 af[4], bfr[4];
#pragma unroll
    for (int i = 0; i < 4; ++i) {
      af[i] = *(const s16x8*)&As[wm + i * 16 + fr][fk];
      bfr[i] = *(const s16x8*)&Bs[wn + i * 16 + fr][fk];
    }
#pragma unroll
    for (int mi = 0; mi < 4; ++mi)
#pragma unroll
      for (int ni = 0; ni < 4; ++ni)
        acc[mi][ni] = __builtin_amdgcn_mfma_f32_16x16x32_bf16(af[mi], bfr[ni], acc[mi][ni], 0, 0, 0);
    __syncthreads();
  }

  // epilogue: D mapping col=lane&15, row=(lane>>4)*4+reg  [verified m89]
  const int er = lane & 15, eq = lane >> 4;
#pragma unroll
  for (int mi = 0; mi < 4; ++mi) {
#pragma unroll
    for (int ni = 0; ni < 4; ++ni) {
#pragma unroll
      for (int r = 0; r < 4; ++r) {
        int row = m0 + wm + mi * 16 + eq * 4 + r;
        int col = n0 + wn + ni * 16 + er;
        float v = acc[mi][ni][r] * scale;
        if (HAS_BIAS) v += bias[col];
        if (RELU) v = v > 0.f ? v : 0.f;
        size_t idx = (size_t)z * cBatch + (size_t)row * N + col;
        if (WF32) Cf[idx] = v;
        if (WB16) Cb[idx] = f2bf(v);
      }
    }
  }
}

// ---------------- row softmax, IN PLACE on bf16 scores [rows][2048] ----------------
__global__ __launch_bounds__(256) void k_softmax(unsigned short* __restrict__ sa) {
  __shared__ float red[4];
  const int row = blockIdx.x;
  const int tid = threadIdx.x;
  unsigned short* sr = sa + (size_t)row * Ss;
  ushort4 u0 = ((const ushort4*)sr)[tid];
  ushort4 u1 = ((const ushort4*)sr)[tid + 256];
  float e[8];
  e[0] = bf2f(u0.x); e[1] = bf2f(u0.y); e[2] = bf2f(u0.z); e[3] = bf2f(u0.w);
  e[4] = bf2f(u1.x); e[5] = bf2f(u1.y); e[6] = bf2f(u1.z); e[7] = bf2f(u1.w);
  float m = fmaxf(fmaxf(fmaxf(e[0], e[1]), fmaxf(e[2], e[3])),
                  fmaxf(fmaxf(e[4], e[5]), fmaxf(e[6], e[7])));
  for (int s = 1; s < 64; s <<= 1) m = fmaxf(m, __shfl_xor(m, s, 64));
  if ((tid & 63) == 0) red[tid >> 6] = m;
  __syncthreads();
  m = fmaxf(fmaxf(red[0], red[1]), fmaxf(red[2], red[3]));
  __syncthreads();
  float sum = 0.f;
#pragma unroll
  for (int j = 0; j < 8; ++j) { e[j] = __expf(e[j] - m); sum += e[j]; }
  for (int s = 1; s < 64; s <<= 1) sum += __shfl_xor(sum, s, 64);
  if ((tid & 63) == 0) red[tid >> 6] = sum;
  __syncthreads();
  sum = red[0] + red[1] + red[2] + red[3];
  float inv = 1.f / sum;
  ushort4 o0, o1;
  o0.x = f2bf(e[0] * inv); o0.y = f2bf(e[1] * inv);
  o0.z = f2bf(e[2] * inv); o0.w = f2bf(e[3] * inv);
  o1.x = f2bf(e[4] * inv); o1.y = f2bf(e[5] * inv);
  o1.z = f2bf(e[6] * inv); o1.w = f2bf(e[7] * inv);
  ((ushort4*)sr)[tid] = o0;
  ((ushort4*)sr)[tid + 256] = o1;
}

// ---------------- residual + LayerNorm ----------------
template <bool A_F32, bool OUT_F32>
__global__ __launch_bounds__(256) void k_ln(const void* __restrict__ a,
                                            const unsigned short* __restrict__ bb,
                                            const float* __restrict__ gamma,
                                            const float* __restrict__ beta,
                                            void* __restrict__ outp) {
  __shared__ float red[4];
  const int row = blockIdx.x;
  const int tid = threadIdx.x;
  float v[4];
  if (A_F32) {
    float4 av = ((const float4*)((const float*)a + (size_t)row * Ee))[tid];
    v[0] = av.x; v[1] = av.y; v[2] = av.z; v[3] = av.w;
  } else {
    ushort4 av = ((const ushort4*)((const unsigned short*)a + (size_t)row * Ee))[tid];
    v[0] = bf2f(av.x); v[1] = bf2f(av.y); v[2] = bf2f(av.z); v[3] = bf2f(av.w);
  }
  ushort4 bv = ((const ushort4*)(bb + (size_t)row * Ee))[tid];
  v[0] += bf2f(bv.x); v[1] += bf2f(bv.y); v[2] += bf2f(bv.z); v[3] += bf2f(bv.w);
  float s = v[0] + v[1] + v[2] + v[3];
  float q = v[0] * v[0] + v[1] * v[1] + v[2] * v[2] + v[3] * v[3];
  for (int sh = 1; sh < 64; sh <<= 1) {
    s += __shfl_xor(s, sh, 64);
    q += __shfl_xor(q, sh, 64);
  }
  if ((tid & 63) == 0) red[tid >> 6] = s;
  __syncthreads();
  s = red[0] + red[1] + red[2] + red[3];
  __syncthreads();
  if ((tid & 63) == 0) red[tid >> 6] = q;
  __syncthreads();
  q = red[0] + red[1] + red[2] + red[3];
  float mu = s * (1.f / Ee);
  float var = q * (1.f / Ee) - mu * mu;
  float rinv = rsqrtf(var + 1e-5f);
  int c = tid * 4;
  float o0 = (v[0] - mu) * rinv * gamma[c + 0] + beta[c + 0];
  float o1 = (v[1] - mu) * rinv * gamma[c + 1] + beta[c + 1];
  float o2 = (v[2] - mu) * rinv * gamma[c + 2] + beta[c + 2];
  float o3 = (v[3] - mu) * rinv * gamma[c + 3] + beta[c + 3];
  if (OUT_F32) {
    float4 o; o.x = o0; o.y = o1; o.z = o2; o.w = o3;
    ((float4*)((float*)outp + (size_t)row * Ee))[tid] = o;
  } else {
    ushort4 o;
    o.x = f2bf(o0); o.y = f2bf(o1); o.z = f2bf(o2); o.w = f2bf(o3);
    ((ushort4*)((unsigned short*)outp + (size_t)row * Ee))[tid] = o;
  }
}

extern "C" void kernel_launch(void* const* d_in, const int* in_sizes, int n_in,
                              void* d_out, int out_size, void* d_ws, size_t ws_size,
                              hipStream_t stream) {
  const float* x = (const float*)d_in[0];
  const float* Wq = (const float*)d_in[1];
  const float* bq = (const float*)d_in[2];
  const float* Wk = (const float*)d_in[3];
  const float* bk = (const float*)d_in[4];
  const float* Wv = (const float*)d_in[5];
  const float* bv = (const float*)d_in[6];
  const float* g1 = (const float*)d_in[7];
  const float* be1 = (const float*)d_in[8];
  const float* W1 = (const float*)d_in[9];
  const float* b1 = (const float*)d_in[10];
  const float* W2 = (const float*)d_in[11];
  const float* b2 = (const float*)d_in[12];
  const float* g2 = (const float*)d_in[13];
  const float* be2 = (const float*)d_in[14];

  float* out = (float*)d_out;          // return order: (out, k, q, v), all f32
  float* kO = out + OUT_SLOT;
  float* qO = out + 2 * OUT_SLOT;
  float* vO = out + 3 * OUT_SLOT;

  char* ws = (char*)d_ws;
  unsigned short* xb  = (unsigned short*)(ws + 0);             // 33.6 MB
  unsigned short* WqT = (unsigned short*)(ws + 33554432ull);   // 2 MB
  unsigned short* WkT = (unsigned short*)(ws + 35651584ull);   // 2 MB
  unsigned short* WvT = (unsigned short*)(ws + 37748736ull);   // 2 MB
  unsigned short* W1T = (unsigned short*)(ws + 39845888ull);   // 8.4 MB  [F][E]
  unsigned short* W2T = (unsigned short*)(ws + 48234496ull);   // 8.4 MB  [E][F]
  unsigned short* qb  = (unsigned short*)(ws + 56623104ull);   // 33.6 MB bf16 q
  unsigned short* kb  = (unsigned short*)(ws + 90177536ull);   // 33.6 MB bf16 k
  unsigned short* vb  = (unsigned short*)(ws + 123731968ull);  // 33.6 MB bf16 v
  unsigned short* scb = (unsigned short*)(ws + 157286400ull);  // 67.1 MB bf16 scores/attn (in-place)
  unsigned short* vT  = (unsigned short*)(ws + 224395264ull);  // 33.6 MB
  unsigned short* ao  = (unsigned short*)(ws + 56623104ull);   // reuse qb (dead after scores)
  unsigned short* hb  = (unsigned short*)(ws + 90177536ull);   // reuse kb (dead after scores)
  unsigned short* f1b = (unsigned short*)(ws + 157286400ull);  // 134.2 MB reuse scb+vT (dead)
  unsigned short* f2b = (unsigned short*)(ws + 123731968ull);  // reuse vb (dead after transpose)

  dim3 tb(32, 8);
  // stage 0: conversions
  k_cvt_f32_bf16<<<2048, 256, 0, stream>>>(x, xb, M_TOK * Ee / 4);
  k_transpose_w<<<dim3(32, 32), tb, 0, stream>>>(Wq, WqT, Ee, Ee);
  k_transpose_w<<<dim3(32, 32), tb, 0, stream>>>(Wk, WkT, Ee, Ee);
  k_transpose_w<<<dim3(32, 32), tb, 0, stream>>>(Wv, WvT, Ee, Ee);
  k_transpose_w<<<dim3(128, 32), tb, 0, stream>>>(W1, W1T, Ee, Ff);
  k_transpose_w<<<dim3(32, 128), tb, 0, stream>>>(W2, W2T, Ff, Ee);
  // stage 1: q,k,v  (dual write: f32 -> d_out slot, bf16 -> ws)
  k_gemm_bt<true, true, false, true><<<dim3(128, 8, 1), 256, 0, stream>>>(
      xb, WqT, qO, qb, bq, M_TOK, Ee, Ee, 0, 0, 0, 1.f);
  k_gemm_bt<true, true, false, true><<<dim3(128, 8, 1), 256, 0, stream>>>(
      xb, WkT, kO, kb, bk, M_TOK, Ee, Ee, 0, 0, 0, 1.f);
  k_gemm_bt<true, true, false, true><<<dim3(128, 8, 1), 256, 0, stream>>>(
      xb, WvT, vO, vb, bv, M_TOK, Ee, Ee, 0, 0, 0, 1.f);
  // stage 2: scores = q @ k^T / 32  (batched over 8) -> bf16
  k_gemm_bt<false, true, false, false><<<dim3(16, 16, 8), 256, 0, stream>>>(
      qb, kb, nullptr, scb, nullptr, Ss, Ss, Ee, (long)Ss * Ee, (long)Ss * Ee, (long)Ss * Ss,
      0.03125f);
  // stage 3: softmax rows, in place
  k_softmax<<<Bb * Ss, 256, 0, stream>>>(scb);
  // stage 4: vT then attn @ v
  k_transpose_v<<<dim3(32, 64, 8), tb, 0, stream>>>(vb, vT);
  k_gemm_bt<false, true, false, false><<<dim3(16, 8, 8), 256, 0, stream>>>(
      scb, vT, nullptr, ao, nullptr, Ss, Ee, Ss, (long)Ss * Ss, (long)Ee * Ss, (long)Ss * Ee, 1.f);
  // stage 5: LN1 -> h (bf16)
  k_ln<true, false><<<M_TOK, 256, 0, stream>>>(x, ao, g1, be1, hb);
  // stage 6: FFN
  k_gemm_bt<false, true, true, true><<<dim3(128, 32, 1), 256, 0, stream>>>(
      hb, W1T, nullptr, f1b, b1, M_TOK, Ff, Ee, 0, 0, 0, 1.f);
  k_gemm_bt<false, true, false, true><<<dim3(128, 8, 1), 256, 0, stream>>>(
      f1b, W2T, nullptr, f2b, b2, M_TOK, Ee, Ff, 0, 0, 0, 1.f);
  // stage 7: LN2 -> out (f32)
  k_ln<false, true><<<M_TOK, 256, 0, stream>>>(hb, f2b, g2, be2, out);
}

// Round 3
// 1025.644 us; speedup vs baseline: 1.0332x; 1.0332x over previous
//
#include <hip/hip_runtime.h>
#include <hip/hip_bf16.h>
#include <stdint.h>

typedef __attribute__((ext_vector_type(8))) short s16x8;
typedef __attribute__((ext_vector_type(4))) float f32x4;

static constexpr int Bb = 8, Ss = 2048, Ee = 1024, Ff = 4096;
static constexpr int M_TOK = Bb * Ss;                      // 16384
static constexpr size_t OUT_SLOT = (size_t)M_TOK * Ee;     // elements per output tensor

__device__ inline unsigned short f2bf(float f) {
  unsigned int u = __float_as_uint(f);
  unsigned int r = (u + 0x7FFFu + ((u >> 16) & 1u)) >> 16;
  return (unsigned short)r;
}
__device__ inline float bf2f(unsigned short h) {
  return __uint_as_float(((unsigned int)h) << 16);
}

// direct HBM -> LDS, 16B per lane; lds dest = wave-uniform base + lane*16
__device__ inline void gload16(const unsigned short* g, unsigned short* l) {
  __builtin_amdgcn_global_load_lds(
      (const __attribute__((address_space(1))) void*)g,
      (__attribute__((address_space(3))) void*)l, 16, 0, 0);
}

// ---------------- elementwise f32 -> bf16 ----------------
__global__ __launch_bounds__(256) void k_cvt_f32_bf16(const float* __restrict__ in,
                                                      unsigned short* __restrict__ out, int n4) {
  int i = blockIdx.x * blockDim.x + threadIdx.x;
  int stride = gridDim.x * blockDim.x;
  for (; i < n4; i += stride) {
    float4 v = ((const float4*)in)[i];
    ushort4 o;
    o.x = f2bf(v.x); o.y = f2bf(v.y); o.z = f2bf(v.z); o.w = f2bf(v.w);
    ((ushort4*)out)[i] = o;
  }
}

// ---------------- transpose+convert W[R][C] f32 -> WT[C][R] bf16 ----------------
__global__ __launch_bounds__(256) void k_transpose_w(const float* __restrict__ in,
                                                     unsigned short* __restrict__ out,
                                                     int R, int C) {
  __shared__ float t[32][33];
  int c0 = blockIdx.x * 32, r0 = blockIdx.y * 32;
  int tx = threadIdx.x, ty = threadIdx.y;
  for (int i = ty; i < 32; i += 8)
    t[i][tx] = in[(size_t)(r0 + i) * C + c0 + tx];
  __syncthreads();
  for (int i = ty; i < 32; i += 8)
    out[(size_t)(c0 + i) * R + r0 + tx] = f2bf(t[tx][i]);
}

// ---------------- per-batch transpose v[S][E] bf16 -> vT[E][S] bf16 ----------------
__global__ __launch_bounds__(256) void k_transpose_v(const unsigned short* __restrict__ v,
                                                     unsigned short* __restrict__ vT) {
  __shared__ unsigned short t[32][33];
  int b = blockIdx.z;
  const unsigned short* in = v + (size_t)b * Ss * Ee;
  unsigned short* out = vT + (size_t)b * Ee * Ss;
  int c0 = blockIdx.x * 32, r0 = blockIdx.y * 32;  // c over E, r over S
  int tx = threadIdx.x, ty = threadIdx.y;
  for (int i = ty; i < 32; i += 8)
    t[i][tx] = in[(size_t)(r0 + i) * Ee + c0 + tx];
  __syncthreads();
  for (int i = ty; i < 32; i += 8)
    out[(size_t)(c0 + i) * Ss + r0 + tx] = t[tx][i];
}

// ---------------- bf16 GEMM (m97 structure): C = A[M,K] @ Bt[N,K]^T * scale ----------------
// 128x128 tile, BK=32, 4 waves (2x2), global_load_lds width-16 staging into
// unpadded LDS [128][32]; each wave 64x64 via 4x4 mfma_f32_16x16x32_bf16 frags.
// Dual output: f32 to Cf (d_out) and/or bf16 to Cb (workspace).
template <bool WF32, bool WB16, bool RELU, bool HAS_BIAS>
__global__ __launch_bounds__(256) void k_gemm_bt(const unsigned short* __restrict__ A,
                                                 const unsigned short* __restrict__ Bt,
                                                 float* __restrict__ Cf,
                                                 unsigned short* __restrict__ Cb,
                                                 const float* __restrict__ bias,
                                                 int M, int N, int K,
                                                 long aBatch, long bBatch, long cBatch,
                                                 float scale) {
  __shared__ unsigned short As[128][32];  // unpadded: required by global_load_lds linear dest
  __shared__ unsigned short Bs[128][32];
  const int tid = threadIdx.x;
  const int lane = tid & 63;
  const int wid = tid >> 6;
  const int wm = (wid >> 1) * 64, wn = (wid & 1) * 64;
  const int m0 = blockIdx.x * 128, n0 = blockIdx.y * 128;
  const int z = blockIdx.z;
  A += (size_t)z * aBatch;
  Bt += (size_t)z * bBatch;

  // staging geometry: wave wid owns chunks {2*wid, 2*wid+1}; chunk c = LDS rows [16c,16c+16).
  // lane l writes LDS bytes l*16 of the chunk -> row_in_chunk = l>>2, col elem = (l&3)*8.
  const int ca = wid * 2;
  const int srow = (lane >> 2);
  const int scol = (lane & 3) * 8;
  const unsigned short* a0 = A + (size_t)(m0 + ca * 16 + srow) * K + scol;
  const unsigned short* a1 = a0 + (size_t)16 * K;
  const unsigned short* b0 = Bt + (size_t)(n0 + ca * 16 + srow) * K + scol;
  const unsigned short* b1 = b0 + (size_t)16 * K;
  unsigned short* ldsA0 = &As[ca * 16][0];
  unsigned short* ldsA1 = &As[ca * 16 + 16][0];
  unsigned short* ldsB0 = &Bs[ca * 16][0];
  unsigned short* ldsB1 = &Bs[ca * 16 + 16][0];

  f32x4 acc[4][4] = {};
  const int fr = lane & 15, fk = (lane >> 4) * 8;

  for (int k0 = 0; k0 < K; k0 += 32) {
    gload16(a0 + k0, ldsA0);
    gload16(a1 + k0, ldsA1);
    gload16(b0 + k0, ldsB0);
    gload16(b1 + k0, ldsB1);
    __syncthreads();
    s16x8 af[4], bfr[4];
#pragma unroll
    for (int i = 0; i < 4; ++i) {
      af[i] = *(const s16x8*)&As[wm + i * 16 + fr][fk];
      bfr[i] = *(const s16x8*)&Bs[wn + i * 16 + fr][fk];
    }
#pragma unroll
    for (int mi = 0; mi < 4; ++mi)
#pragma unroll
      for (int ni = 0; ni < 4; ++ni)
        acc[mi][ni] = __builtin_amdgcn_mfma_f32_16x16x32_bf16(af[mi], bfr[ni], acc[mi][ni], 0, 0, 0);
    __syncthreads();
  }

  // epilogue: D mapping col=lane&15, row=(lane>>4)*4+reg  [verified m89]
  const int er = lane & 15, eq = lane >> 4;
#pragma unroll
  for (int mi = 0; mi < 4; ++mi) {
#pragma unroll
    for (int ni = 0; ni < 4; ++ni) {
#pragma unroll
      for (int r = 0; r < 4; ++r) {
        int row = m0 + wm + mi * 16 + eq * 4 + r;
        int col = n0 + wn + ni * 16 + er;
        float v = acc[mi][ni][r] * scale;
        if (HAS_BIAS) v += bias[col];
        if (RELU) v = v > 0.f ? v : 0.f;
        size_t idx = (size_t)z * cBatch + (size_t)row * N + col;
        if (WF32) Cf[idx] = v;
        if (WB16) Cb[idx] = f2bf(v);
      }
    }
  }
}

// ---------------- row softmax, IN PLACE on bf16 scores [rows][2048] ----------------
__global__ __launch_bounds__(256) void k_softmax(unsigned short* __restrict__ sa) {
  __shared__ float red[4];
  const int row = blockIdx.x;
  const int tid = threadIdx.x;
  unsigned short* sr = sa + (size_t)row * Ss;
  ushort4 u0 = ((const ushort4*)sr)[tid];
  ushort4 u1 = ((const ushort4*)sr)[tid + 256];
  float e[8];
  e[0] = bf2f(u0.x); e[1] = bf2f(u0.y); e[2] = bf2f(u0.z); e[3] = bf2f(u0.w);
  e[4] = bf2f(u1.x); e[5] = bf2f(u1.y); e[6] = bf2f(u1.z); e[7] = bf2f(u1.w);
  float m = fmaxf(fmaxf(fmaxf(e[0], e[1]), fmaxf(e[2], e[3])),
                  fmaxf(fmaxf(e[4], e[5]), fmaxf(e[6], e[7])));
  for (int s = 1; s < 64; s <<= 1) m = fmaxf(m, __shfl_xor(m, s, 64));
  if ((tid & 63) == 0) red[tid >> 6] = m;
  __syncthreads();
  m = fmaxf(fmaxf(red[0], red[1]), fmaxf(red[2], red[3]));
  __syncthreads();
  float sum = 0.f;
#pragma unroll
  for (int j = 0; j < 8; ++j) { e[j] = __expf(e[j] - m); sum += e[j]; }
  for (int s = 1; s < 64; s <<= 1) sum += __shfl_xor(sum, s, 64);
  if ((tid & 63) == 0) red[tid >> 6] = sum;
  __syncthreads();
  sum = red[0] + red[1] + red[2] + red[3];
  float inv = 1.f / sum;
  ushort4 o0, o1;
  o0.x = f2bf(e[0] * inv); o0.y = f2bf(e[1] * inv);
  o0.z = f2bf(e[2] * inv); o0.w = f2bf(e[3] * inv);
  o1.x = f2bf(e[4] * inv); o1.y = f2bf(e[5] * inv);
  o1.z = f2bf(e[6] * inv); o1.w = f2bf(e[7] * inv);
  ((ushort4*)sr)[tid] = o0;
  ((ushort4*)sr)[tid + 256] = o1;
}

// ---------------- residual + LayerNorm ----------------
template <bool A_F32, bool OUT_F32>
__global__ __launch_bounds__(256) void k_ln(const void* __restrict__ a,
                                            const unsigned short* __restrict__ bb,
                                            const float* __restrict__ gamma,
                                            const float* __restrict__ beta,
                                            void* __restrict__ outp) {
  __shared__ float red[4];
  const int row = blockIdx.x;
  const int tid = threadIdx.x;
  float v[4];
  if (A_F32) {
    float4 av = ((const float4*)((const float*)a + (size_t)row * Ee))[tid];
    v[0] = av.x; v[1] = av.y; v[2] = av.z; v[3] = av.w;
  } else {
    ushort4 av = ((const ushort4*)((const unsigned short*)a + (size_t)row * Ee))[tid];
    v[0] = bf2f(av.x); v[1] = bf2f(av.y); v[2] = bf2f(av.z); v[3] = bf2f(av.w);
  }
  ushort4 bv = ((const ushort4*)(bb + (size_t)row * Ee))[tid];
  v[0] += bf2f(bv.x); v[1] += bf2f(bv.y); v[2] += bf2f(bv.z); v[3] += bf2f(bv.w);
  float s = v[0] + v[1] + v[2] + v[3];
  float q = v[0] * v[0] + v[1] * v[1] + v[2] * v[2] + v[3] * v[3];
  for (int sh = 1; sh < 64; sh <<= 1) {
    s += __shfl_xor(s, sh, 64);
    q += __shfl_xor(q, sh, 64);
  }
  if ((tid & 63) == 0) red[tid >> 6] = s;
  __syncthreads();
  s = red[0] + red[1] + red[2] + red[3];
  __syncthreads();
  if ((tid & 63) == 0) red[tid >> 6] = q;
  __syncthreads();
  q = red[0] + red[1] + red[2] + red[3];
  float mu = s * (1.f / Ee);
  float var = q * (1.f / Ee) - mu * mu;
  float rinv = rsqrtf(var + 1e-5f);
  int c = tid * 4;
  float o0 = (v[0] - mu) * rinv * gamma[c + 0] + beta[c + 0];
  float o1 = (v[1] - mu) * rinv * gamma[c + 1] + beta[c + 1];
  float o2 = (v[2] - mu) * rinv * gamma[c + 2] + beta[c + 2];
  float o3 = (v[3] - mu) * rinv * gamma[c + 3] + beta[c + 3];
  if (OUT_F32) {
    float4 o; o.x = o0; o.y = o1; o.z = o2; o.w = o3;
    ((float4*)((float*)outp + (size_t)row * Ee))[tid] = o;
  } else {
    ushort4 o;
    o.x = f2bf(o0); o.y = f2bf(o1); o.z = f2bf(o2); o.w = f2bf(o3);
    ((ushort4*)((unsigned short*)outp + (size_t)row * Ee))[tid] = o;
  }
}

extern "C" void kernel_launch(void* const* d_in, const int* in_sizes, int n_in,
                              void* d_out, int out_size, void* d_ws, size_t ws_size,
                              hipStream_t stream) {
  const float* x = (const float*)d_in[0];
  const float* Wq = (const float*)d_in[1];
  const float* bq = (const float*)d_in[2];
  const float* Wk = (const float*)d_in[3];
  const float* bk = (const float*)d_in[4];
  const float* Wv = (const float*)d_in[5];
  const float* bv = (const float*)d_in[6];
  const float* g1 = (const float*)d_in[7];
  const float* be1 = (const float*)d_in[8];
  const float* W1 = (const float*)d_in[9];
  const float* b1 = (const float*)d_in[10];
  const float* W2 = (const float*)d_in[11];
  const float* b2 = (const float*)d_in[12];
  const float* g2 = (const float*)d_in[13];
  const float* be2 = (const float*)d_in[14];

  float* out = (float*)d_out;          // return order: (out, k, q, v), all f32
  float* kO = out + OUT_SLOT;
  float* qO = out + 2 * OUT_SLOT;
  float* vO = out + 3 * OUT_SLOT;

  char* ws = (char*)d_ws;
  unsigned short* xb  = (unsigned short*)(ws + 0);             // 33.6 MB
  unsigned short* WqT = (unsigned short*)(ws + 33554432ull);   // 2 MB
  unsigned short* WkT = (unsigned short*)(ws + 35651584ull);   // 2 MB
  unsigned short* WvT = (unsigned short*)(ws + 37748736ull);   // 2 MB
  unsigned short* W1T = (unsigned short*)(ws + 39845888ull);   // 8.4 MB  [F][E]
  unsigned short* W2T = (unsigned short*)(ws + 48234496ull);   // 8.4 MB  [E][F]
  unsigned short* qb  = (unsigned short*)(ws + 56623104ull);   // 33.6 MB bf16 q
  unsigned short* kb  = (unsigned short*)(ws + 90177536ull);   // 33.6 MB bf16 k
  unsigned short* vb  = (unsigned short*)(ws + 123731968ull);  // 33.6 MB bf16 v
  unsigned short* scb = (unsigned short*)(ws + 157286400ull);  // 67.1 MB bf16 scores/attn (in-place)
  unsigned short* vT  = (unsigned short*)(ws + 224395264ull);  // 33.6 MB
  unsigned short* ao  = (unsigned short*)(ws + 56623104ull);   // reuse qb (dead after scores)
  unsigned short* hb  = (unsigned short*)(ws + 90177536ull);   // reuse kb (dead after scores)
  unsigned short* f1b = (unsigned short*)(ws + 157286400ull);  // 134.2 MB reuse scb+vT (dead)
  unsigned short* f2b = (unsigned short*)(ws + 123731968ull);  // reuse vb (dead after transpose)

  dim3 tb(32, 8);
  // stage 0: conversions
  k_cvt_f32_bf16<<<2048, 256, 0, stream>>>(x, xb, M_TOK * Ee / 4);
  k_transpose_w<<<dim3(32, 32), tb, 0, stream>>>(Wq, WqT, Ee, Ee);
  k_transpose_w<<<dim3(32, 32), tb, 0, stream>>>(Wk, WkT, Ee, Ee);
  k_transpose_w<<<dim3(32, 32), tb, 0, stream>>>(Wv, WvT, Ee, Ee);
  k_transpose_w<<<dim3(128, 32), tb, 0, stream>>>(W1, W1T, Ee, Ff);
  k_transpose_w<<<dim3(32, 128), tb, 0, stream>>>(W2, W2T, Ff, Ee);
  // stage 1: q,k,v  (dual write: f32 -> d_out slot, bf16 -> ws)
  k_gemm_bt<true, true, false, true><<<dim3(128, 8, 1), 256, 0, stream>>>(
      xb, WqT, qO, qb, bq, M_TOK, Ee, Ee, 0, 0, 0, 1.f);
  k_gemm_bt<true, true, false, true><<<dim3(128, 8, 1), 256, 0, stream>>>(
      xb, WkT, kO, kb, bk, M_TOK, Ee, Ee, 0, 0, 0, 1.f);
  k_gemm_bt<true, true, false, true><<<dim3(128, 8, 1), 256, 0, stream>>>(
      xb, WvT, vO, vb, bv, M_TOK, Ee, Ee, 0, 0, 0, 1.f);
  // stage 2: scores = q @ k^T / 32  (batched over 8) -> bf16
  k_gemm_bt<false, true, false, false><<<dim3(16, 16, 8), 256, 0, stream>>>(
      qb, kb, nullptr, scb, nullptr, Ss, Ss, Ee, (long)Ss * Ee, (long)Ss * Ee, (long)Ss * Ss,
      0.03125f);
  // stage 3: softmax rows, in place
  k_softmax<<<Bb * Ss, 256, 0, stream>>>(scb);
  // stage 4: vT then attn @ v
  k_transpose_v<<<dim3(32, 64, 8), tb, 0, stream>>>(vb, vT);
  k_gemm_bt<false, true, false, false><<<dim3(16, 8, 8), 256, 0, stream>>>(
      scb, vT, nullptr, ao, nullptr, Ss, Ee, Ss, (long)Ss * Ss, (long)Ee * Ss, (long)Ss * Ee, 1.f);
  // stage 5: LN1 -> h (bf16)
  k_ln<true, false><<<M_TOK, 256, 0, stream>>>(x, ao, g1, be1, hb);
  // stage 6: FFN
  k_gemm_bt<false, true, true, true><<<dim3(128, 32, 1), 256, 0, stream>>>(
      hb, W1T, nullptr, f1b, b1, M_TOK, Ff, Ee, 0, 0, 0, 1.f);
  k_gemm_bt<false, true, false, true><<<dim3(128, 8, 1), 256, 0, stream>>>(
      f1b, W2T, nullptr, f2b, b2, M_TOK, Ee, Ff, 0, 0, 0, 1.f);
  // stage 7: LN2 -> out (f32)
  k_ln<false, true><<<M_TOK, 256, 0, stream>>>(hb, f2b, g2, be2, out);
}

// Round 4
// 798.672 us; speedup vs baseline: 1.3268x; 1.2842x over previous
//
#include <hip/hip_runtime.h>
#include <hip/hip_bf16.h>
#include <stdint.h>

typedef __attribute__((ext_vector_type(8))) short s16x8;
typedef __attribute__((ext_vector_type(4))) float f32x4;

static constexpr int Bb = 8, Ss = 2048, Ee = 1024, Ff = 4096;
static constexpr int M_TOK = Bb * Ss;                      // 16384
static constexpr size_t OUT_SLOT = (size_t)M_TOK * Ee;     // elements per output tensor

__device__ inline unsigned short f2bf(float f) {
  unsigned int u = __float_as_uint(f);
  unsigned int r = (u + 0x7FFFu + ((u >> 16) & 1u)) >> 16;
  return (unsigned short)r;
}
__device__ inline float bf2f(unsigned short h) {
  return __uint_as_float(((unsigned int)h) << 16);
}

// direct HBM -> LDS, 16B per lane; lds dest = wave-uniform base + lane*16
__device__ inline void gload16(const unsigned short* g, const unsigned short* l) {
  __builtin_amdgcn_global_load_lds(
      (const __attribute__((address_space(1))) void*)g,
      (__attribute__((address_space(3))) void*)(unsigned short*)l, 16, 0, 0);
}

// ---------------- elementwise f32 -> bf16 ----------------
__global__ __launch_bounds__(256) void k_cvt_f32_bf16(const float* __restrict__ in,
                                                      unsigned short* __restrict__ out, int n4) {
  int i = blockIdx.x * blockDim.x + threadIdx.x;
  int stride = gridDim.x * blockDim.x;
  for (; i < n4; i += stride) {
    float4 v = ((const float4*)in)[i];
    ushort4 o;
    o.x = f2bf(v.x); o.y = f2bf(v.y); o.z = f2bf(v.z); o.w = f2bf(v.w);
    ((ushort4*)out)[i] = o;
  }
}

// ---------------- transpose+convert W[R][C] f32 -> WT[C][R] bf16 ----------------
__global__ __launch_bounds__(256) void k_transpose_w(const float* __restrict__ in,
                                                     unsigned short* __restrict__ out,
                                                     int R, int C) {
  __shared__ float t[32][33];
  int c0 = blockIdx.x * 32, r0 = blockIdx.y * 32;
  int tx = threadIdx.x, ty = threadIdx.y;
  for (int i = ty; i < 32; i += 8)
    t[i][tx] = in[(size_t)(r0 + i) * C + c0 + tx];
  __syncthreads();
  for (int i = ty; i < 32; i += 8)
    out[(size_t)(c0 + i) * R + r0 + tx] = f2bf(t[tx][i]);
}

// ---------------- per-batch transpose v[S][E] bf16 -> vT[E][S] bf16 ----------------
__global__ __launch_bounds__(256) void k_transpose_v(const unsigned short* __restrict__ v,
                                                     unsigned short* __restrict__ vT) {
  __shared__ unsigned short t[32][33];
  int b = blockIdx.z;
  const unsigned short* in = v + (size_t)b * Ss * Ee;
  unsigned short* out = vT + (size_t)b * Ee * Ss;
  int c0 = blockIdx.x * 32, r0 = blockIdx.y * 32;  // c over E, r over S
  int tx = threadIdx.x, ty = threadIdx.y;
  for (int i = ty; i < 32; i += 8)
    t[i][tx] = in[(size_t)(r0 + i) * Ee + c0 + tx];
  __syncthreads();
  for (int i = ty; i < 32; i += 8)
    out[(size_t)(c0 + i) * Ss + r0 + tx] = t[tx][i];
}

// ---------------- 256x256 pipelined bf16 GEMM: C = A[M,K] @ Bt[N,K]^T * scale ----------------
// 8 waves (2M x 4N), per-wave 128x64 output (8x4 frags of 16x16x32).
// LDS: 4-slot ring of BK=32 K-steps, 2 matrices, [256][32] bf16 each = 128 KiB.
// Counted vmcnt (12 steady; tail 8/4/0), raw s_barrier (no drain), T2 chunk-XOR
// swizzle (chunk ^= row&3) applied on gload source AND ds_read addr, T5 setprio.
// M, N multiples of 256; K multiple of 32, K/32 >= 4.
template <bool WF32, bool WB16, bool RELU, bool HAS_BIAS>
__global__ __launch_bounds__(512, 2) void k_gemm256(const unsigned short* __restrict__ A,
                                                    const unsigned short* __restrict__ Bt,
                                                    float* __restrict__ Cf,
                                                    unsigned short* __restrict__ Cb,
                                                    const float* __restrict__ bias,
                                                    int M, int N, int K,
                                                    long aBatch, long bBatch, long cBatch,
                                                    float scale) {
  __shared__ unsigned short lds[4][2][256 * 32];  // [slot][A|B][row*32+chunk*8] 128 KiB
  const int tid = threadIdx.x;
  const int lane = tid & 63;
  const int wid = tid >> 6;              // 0..7
  const int wr = wid >> 2, wc = wid & 3; // 2 x 4 wave grid

  // T1: bijective XCD swizzle on flattened (x,y); all our grids have nwg % 8 == 0
  const int gx = gridDim.x;
  const int nwg = gx * gridDim.y;
  const int id = blockIdx.y * gx + blockIdx.x;
  const int qq = nwg >> 3;
  const int sid = (id & 7) * qq + (id >> 3);
  const int m0 = (sid % gx) * 256, n0 = (sid / gx) * 256;
  const int z = blockIdx.z;
  A += (size_t)z * aBatch;
  Bt += (size_t)z * bBatch;

  // staging: per K-step, per matrix, thread does 2 gload16.
  // linear dest elem = j*4096 + tid*8  ->  row = j*128 + tid/4, chunk_dst = tid&3.
  // source chunk = chunk_dst ^ (row&3)  (involution; row&3 == (tid>>2)&3 for both j)
  const int srow = tid >> 2;
  const int csrc = (tid & 3) ^ (srow & 3);
  const unsigned short* ga0 = A + (size_t)(m0 + srow) * K + csrc * 8;
  const unsigned short* ga1 = A + (size_t)(m0 + 128 + srow) * K + csrc * 8;
  const unsigned short* gb0 = Bt + (size_t)(n0 + srow) * K + csrc * 8;
  const unsigned short* gb1 = Bt + (size_t)(n0 + 128 + srow) * K + csrc * 8;
  const int waveDst = (wid << 9);  // wave-uniform LDS elem offset; +lane*8 implicit

  auto STAGE = [&](int step) {
    const int slot = step & 3;
    const size_t ko = (size_t)step << 5;
    const unsigned short* la = &lds[slot][0][0];
    const unsigned short* lb = &lds[slot][1][0];
    gload16(ga0 + ko, la + waveDst);
    gload16(ga1 + ko, la + 4096 + waveDst);
    gload16(gb0 + ko, lb + waveDst);
    gload16(gb1 + ko, lb + 4096 + waveDst);
  };

  f32x4 acc[8][4] = {};
  const int fr = lane & 15;
  const int cc = ((lane >> 4) ^ (fr & 3)) * 8;  // swizzled chunk elem offset
  const int nt = K >> 5;

  STAGE(0); STAGE(1); STAGE(2);

  for (int t = 0; t < nt; ++t) {
    if (t + 3 < nt) {
      STAGE(t + 3);
      asm volatile("s_waitcnt vmcnt(12)" ::: "memory");
    } else {
      const int rem = nt - 1 - t;
      if (rem == 2)      asm volatile("s_waitcnt vmcnt(8)" ::: "memory");
      else if (rem == 1) asm volatile("s_waitcnt vmcnt(4)" ::: "memory");
      else               asm volatile("s_waitcnt vmcnt(0)" ::: "memory");
    }
    __builtin_amdgcn_s_barrier();
    asm volatile("" ::: "memory");

    const int slot = t & 3;
    const unsigned short* la = &lds[slot][0][0];
    const unsigned short* lb = &lds[slot][1][0];
    __builtin_amdgcn_s_setprio(1);
    s16x8 bf[4];
#pragma unroll
    for (int ni = 0; ni < 4; ++ni)
      bf[ni] = *(const s16x8*)(lb + ((wc * 64 + ni * 16 + fr) * 32 + cc));
#pragma unroll
    for (int mi = 0; mi < 8; ++mi) {
      s16x8 af = *(const s16x8*)(la + ((wr * 128 + mi * 16 + fr) * 32 + cc));
#pragma unroll
      for (int ni = 0; ni < 4; ++ni)
        acc[mi][ni] = __builtin_amdgcn_mfma_f32_16x16x32_bf16(af, bf[ni], acc[mi][ni], 0, 0, 0);
    }
    __builtin_amdgcn_s_setprio(0);
    asm volatile("" ::: "memory");
    __builtin_amdgcn_s_barrier();
  }

  // epilogue: D mapping col=lane&15, row=(lane>>4)*4+reg  [verified m89]
  const int er = lane & 15, eq = lane >> 4;
#pragma unroll
  for (int mi = 0; mi < 8; ++mi) {
#pragma unroll
    for (int ni = 0; ni < 4; ++ni) {
#pragma unroll
      for (int r = 0; r < 4; ++r) {
        int row = m0 + wr * 128 + mi * 16 + eq * 4 + r;
        int col = n0 + wc * 64 + ni * 16 + er;
        float v = acc[mi][ni][r] * scale;
        if (HAS_BIAS) v += bias[col];
        if (RELU) v = v > 0.f ? v : 0.f;
        size_t idx = (size_t)z * cBatch + (size_t)row * N + col;
        if (WF32) Cf[idx] = v;
        if (WB16) Cb[idx] = f2bf(v);
      }
    }
  }
}

// ---------------- row softmax, IN PLACE on bf16 scores [rows][2048] ----------------
__global__ __launch_bounds__(256) void k_softmax(unsigned short* __restrict__ sa) {
  __shared__ float red[4];
  const int row = blockIdx.x;
  const int tid = threadIdx.x;
  unsigned short* sr = sa + (size_t)row * Ss;
  ushort4 u0 = ((const ushort4*)sr)[tid];
  ushort4 u1 = ((const ushort4*)sr)[tid + 256];
  float e[8];
  e[0] = bf2f(u0.x); e[1] = bf2f(u0.y); e[2] = bf2f(u0.z); e[3] = bf2f(u0.w);
  e[4] = bf2f(u1.x); e[5] = bf2f(u1.y); e[6] = bf2f(u1.z); e[7] = bf2f(u1.w);
  float m = fmaxf(fmaxf(fmaxf(e[0], e[1]), fmaxf(e[2], e[3])),
                  fmaxf(fmaxf(e[4], e[5]), fmaxf(e[6], e[7])));
  for (int s = 1; s < 64; s <<= 1) m = fmaxf(m, __shfl_xor(m, s, 64));
  if ((tid & 63) == 0) red[tid >> 6] = m;
  __syncthreads();
  m = fmaxf(fmaxf(red[0], red[1]), fmaxf(red[2], red[3]));
  __syncthreads();
  float sum = 0.f;
#pragma unroll
  for (int j = 0; j < 8; ++j) { e[j] = __expf(e[j] - m); sum += e[j]; }
  for (int s = 1; s < 64; s <<= 1) sum += __shfl_xor(sum, s, 64);
  if ((tid & 63) == 0) red[tid >> 6] = sum;
  __syncthreads();
  sum = red[0] + red[1] + red[2] + red[3];
  float inv = 1.f / sum;
  ushort4 o0, o1;
  o0.x = f2bf(e[0] * inv); o0.y = f2bf(e[1] * inv);
  o0.z = f2bf(e[2] * inv); o0.w = f2bf(e[3] * inv);
  o1.x = f2bf(e[4] * inv); o1.y = f2bf(e[5] * inv);
  o1.z = f2bf(e[6] * inv); o1.w = f2bf(e[7] * inv);
  ((ushort4*)sr)[tid] = o0;
  ((ushort4*)sr)[tid + 256] = o1;
}

// ---------------- residual + LayerNorm ----------------
template <bool A_F32, bool OUT_F32>
__global__ __launch_bounds__(256) void k_ln(const void* __restrict__ a,
                                            const unsigned short* __restrict__ bb,
                                            const float* __restrict__ gamma,
                                            const float* __restrict__ beta,
                                            void* __restrict__ outp) {
  __shared__ float red[4];
  const int row = blockIdx.x;
  const int tid = threadIdx.x;
  float v[4];
  if (A_F32) {
    float4 av = ((const float4*)((const float*)a + (size_t)row * Ee))[tid];
    v[0] = av.x; v[1] = av.y; v[2] = av.z; v[3] = av.w;
  } else {
    ushort4 av = ((const ushort4*)((const unsigned short*)a + (size_t)row * Ee))[tid];
    v[0] = bf2f(av.x); v[1] = bf2f(av.y); v[2] = bf2f(av.z); v[3] = bf2f(av.w);
  }
  ushort4 bv = ((const ushort4*)(bb + (size_t)row * Ee))[tid];
  v[0] += bf2f(bv.x); v[1] += bf2f(bv.y); v[2] += bf2f(bv.z); v[3] += bf2f(bv.w);
  float s = v[0] + v[1] + v[2] + v[3];
  float q = v[0] * v[0] + v[1] * v[1] + v[2] * v[2] + v[3] * v[3];
  for (int sh = 1; sh < 64; sh <<= 1) {
    s += __shfl_xor(s, sh, 64);
    q += __shfl_xor(q, sh, 64);
  }
  if ((tid & 63) == 0) red[tid >> 6] = s;
  __syncthreads();
  s = red[0] + red[1] + red[2] + red[3];
  __syncthreads();
  if ((tid & 63) == 0) red[tid >> 6] = q;
  __syncthreads();
  q = red[0] + red[1] + red[2] + red[3];
  float mu = s * (1.f / Ee);
  float var = q * (1.f / Ee) - mu * mu;
  float rinv = rsqrtf(var + 1e-5f);
  int c = tid * 4;
  float o0 = (v[0] - mu) * rinv * gamma[c + 0] + beta[c + 0];
  float o1 = (v[1] - mu) * rinv * gamma[c + 1] + beta[c + 1];
  float o2 = (v[2] - mu) * rinv * gamma[c + 2] + beta[c + 2];
  float o3 = (v[3] - mu) * rinv * gamma[c + 3] + beta[c + 3];
  if (OUT_F32) {
    float4 o; o.x = o0; o.y = o1; o.z = o2; o.w = o3;
    ((float4*)((float*)outp + (size_t)row * Ee))[tid] = o;
  } else {
    ushort4 o;
    o.x = f2bf(o0); o.y = f2bf(o1); o.z = f2bf(o2); o.w = f2bf(o3);
    ((ushort4*)((unsigned short*)outp + (size_t)row * Ee))[tid] = o;
  }
}

extern "C" void kernel_launch(void* const* d_in, const int* in_sizes, int n_in,
                              void* d_out, int out_size, void* d_ws, size_t ws_size,
                              hipStream_t stream) {
  const float* x = (const float*)d_in[0];
  const float* Wq = (const float*)d_in[1];
  const float* bq = (const float*)d_in[2];
  const float* Wk = (const float*)d_in[3];
  const float* bk = (const float*)d_in[4];
  const float* Wv = (const float*)d_in[5];
  const float* bv = (const float*)d_in[6];
  const float* g1 = (const float*)d_in[7];
  const float* be1 = (const float*)d_in[8];
  const float* W1 = (const float*)d_in[9];
  const float* b1 = (const float*)d_in[10];
  const float* W2 = (const float*)d_in[11];
  const float* b2 = (const float*)d_in[12];
  const float* g2 = (const float*)d_in[13];
  const float* be2 = (const float*)d_in[14];

  float* out = (float*)d_out;          // return order: (out, k, q, v), all f32
  float* kO = out + OUT_SLOT;
  float* qO = out + 2 * OUT_SLOT;
  float* vO = out + 3 * OUT_SLOT;

  char* ws = (char*)d_ws;
  unsigned short* xb  = (unsigned short*)(ws + 0);             // 33.6 MB
  unsigned short* WqT = (unsigned short*)(ws + 33554432ull);   // 2 MB
  unsigned short* WkT = (unsigned short*)(ws + 35651584ull);   // 2 MB
  unsigned short* WvT = (unsigned short*)(ws + 37748736ull);   // 2 MB
  unsigned short* W1T = (unsigned short*)(ws + 39845888ull);   // 8.4 MB  [F][E]
  unsigned short* W2T = (unsigned short*)(ws + 48234496ull);   // 8.4 MB  [E][F]
  unsigned short* qb  = (unsigned short*)(ws + 56623104ull);   // 33.6 MB bf16 q
  unsigned short* kb  = (unsigned short*)(ws + 90177536ull);   // 33.6 MB bf16 k
  unsigned short* vb  = (unsigned short*)(ws + 123731968ull);  // 33.6 MB bf16 v
  unsigned short* scb = (unsigned short*)(ws + 157286400ull);  // 67.1 MB bf16 scores/attn (in-place)
  unsigned short* vT  = (unsigned short*)(ws + 224395264ull);  // 33.6 MB
  unsigned short* ao  = (unsigned short*)(ws + 56623104ull);   // reuse qb (dead after scores)
  unsigned short* hb  = (unsigned short*)(ws + 90177536ull);   // reuse kb (dead after scores)
  unsigned short* f1b = (unsigned short*)(ws + 157286400ull);  // 134.2 MB reuse scb+vT (dead)
  unsigned short* f2b = (unsigned short*)(ws + 123731968ull);  // reuse vb (dead after transpose)

  dim3 tb(32, 8);
  // stage 0: conversions
  k_cvt_f32_bf16<<<2048, 256, 0, stream>>>(x, xb, M_TOK * Ee / 4);
  k_transpose_w<<<dim3(32, 32), tb, 0, stream>>>(Wq, WqT, Ee, Ee);
  k_transpose_w<<<dim3(32, 32), tb, 0, stream>>>(Wk, WkT, Ee, Ee);
  k_transpose_w<<<dim3(32, 32), tb, 0, stream>>>(Wv, WvT, Ee, Ee);
  k_transpose_w<<<dim3(128, 32), tb, 0, stream>>>(W1, W1T, Ee, Ff);
  k_transpose_w<<<dim3(32, 128), tb, 0, stream>>>(W2, W2T, Ff, Ee);
  // stage 1: q,k,v  (dual write: f32 -> d_out slot, bf16 -> ws)
  k_gemm256<true, true, false, true><<<dim3(64, 4, 1), 512, 0, stream>>>(
      xb, WqT, qO, qb, bq, M_TOK, Ee, Ee, 0, 0, 0, 1.f);
  k_gemm256<true, true, false, true><<<dim3(64, 4, 1), 512, 0, stream>>>(
      xb, WkT, kO, kb, bk, M_TOK, Ee, Ee, 0, 0, 0, 1.f);
  k_gemm256<true, true, false, true><<<dim3(64, 4, 1), 512, 0, stream>>>(
      xb, WvT, vO, vb, bv, M_TOK, Ee, Ee, 0, 0, 0, 1.f);
  // stage 2: scores = q @ k^T / 32  (batched over 8) -> bf16
  k_gemm256<false, true, false, false><<<dim3(8, 8, 8), 512, 0, stream>>>(
      qb, kb, nullptr, scb, nullptr, Ss, Ss, Ee, (long)Ss * Ee, (long)Ss * Ee, (long)Ss * Ss,
      0.03125f);
  // stage 3: softmax rows, in place
  k_softmax<<<Bb * Ss, 256, 0, stream>>>(scb);
  // stage 4: vT then attn @ v
  k_transpose_v<<<dim3(32, 64, 8), tb, 0, stream>>>(vb, vT);
  k_gemm256<false, true, false, false><<<dim3(8, 4, 8), 512, 0, stream>>>(
      scb, vT, nullptr, ao, nullptr, Ss, Ee, Ss, (long)Ss * Ss, (long)Ee * Ss, (long)Ss * Ee, 1.f);
  // stage 5: LN1 -> h (bf16)
  k_ln<true, false><<<M_TOK, 256, 0, stream>>>(x, ao, g1, be1, hb);
  // stage 6: FFN
  k_gemm256<false, true, true, true><<<dim3(64, 16, 1), 512, 0, stream>>>(
      hb, W1T, nullptr, f1b, b1, M_TOK, Ff, Ee, 0, 0, 0, 1.f);
  k_gemm256<false, true, false, true><<<dim3(64, 4, 1), 512, 0, stream>>>(
      f1b, W2T, nullptr, f2b, b2, M_TOK, Ee, Ff, 0, 0, 0, 1.f);
  // stage 7: LN2 -> out (f32)
  k_ln<false, true><<<M_TOK, 256, 0, stream>>>(hb, f2b, g2, be2, out);
}

// Round 5
// 735.464 us; speedup vs baseline: 1.4409x; 1.0859x over previous
//
#include <hip/hip_runtime.h>
#include <hip/hip_bf16.h>
#include <stdint.h>

typedef __attribute__((ext_vector_type(8))) short s16x8;
typedef __attribute__((ext_vector_type(4))) float f32x4;

static constexpr int Bb = 8, Ss = 2048, Ee = 1024, Ff = 4096;
static constexpr int M_TOK = Bb * Ss;                      // 16384
static constexpr size_t OUT_SLOT = (size_t)M_TOK * Ee;     // elements per output tensor

__device__ inline unsigned short f2bf(float f) {
  unsigned int u = __float_as_uint(f);
  unsigned int r = (u + 0x7FFFu + ((u >> 16) & 1u)) >> 16;
  return (unsigned short)r;
}
__device__ inline float bf2f(unsigned short h) {
  return __uint_as_float(((unsigned int)h) << 16);
}

// direct HBM -> LDS, 16B per lane; lds dest = wave-uniform base + lane*16
__device__ inline void gload16(const unsigned short* g, const unsigned short* l) {
  __builtin_amdgcn_global_load_lds(
      (const __attribute__((address_space(1))) void*)g,
      (__attribute__((address_space(3))) void*)(unsigned short*)l, 16, 0, 0);
}

// ---------------- elementwise f32 -> bf16 ----------------
__global__ __launch_bounds__(256) void k_cvt_f32_bf16(const float* __restrict__ in,
                                                      unsigned short* __restrict__ out, int n4) {
  int i = blockIdx.x * blockDim.x + threadIdx.x;
  int stride = gridDim.x * blockDim.x;
  for (; i < n4; i += stride) {
    float4 v = ((const float4*)in)[i];
    ushort4 o;
    o.x = f2bf(v.x); o.y = f2bf(v.y); o.z = f2bf(v.z); o.w = f2bf(v.w);
    ((ushort4*)out)[i] = o;
  }
}

// ---------------- transpose+convert W[R][C] f32 -> WT[C][R] bf16 ----------------
__global__ __launch_bounds__(256) void k_transpose_w(const float* __restrict__ in,
                                                     unsigned short* __restrict__ out,
                                                     int R, int C) {
  __shared__ float t[32][33];
  int c0 = blockIdx.x * 32, r0 = blockIdx.y * 32;
  int tx = threadIdx.x, ty = threadIdx.y;
  for (int i = ty; i < 32; i += 8)
    t[i][tx] = in[(size_t)(r0 + i) * C + c0 + tx];
  __syncthreads();
  for (int i = ty; i < 32; i += 8)
    out[(size_t)(c0 + i) * R + r0 + tx] = f2bf(t[tx][i]);
}

// ---------------- per-batch transpose v[S][E] bf16 -> vT[E][S] bf16 ----------------
__global__ __launch_bounds__(256) void k_transpose_v(const unsigned short* __restrict__ v,
                                                     unsigned short* __restrict__ vT) {
  __shared__ unsigned short t[32][33];
  int b = blockIdx.z;
  const unsigned short* in = v + (size_t)b * Ss * Ee;
  unsigned short* out = vT + (size_t)b * Ee * Ss;
  int c0 = blockIdx.x * 32, r0 = blockIdx.y * 32;  // c over E, r over S
  int tx = threadIdx.x, ty = threadIdx.y;
  for (int i = ty; i < 32; i += 8)
    t[i][tx] = in[(size_t)(r0 + i) * Ee + c0 + tx];
  __syncthreads();
  for (int i = ty; i < 32; i += 8)
    out[(size_t)(c0 + i) * Ss + r0 + tx] = t[tx][i];
}

// ---------------- 256x256 phase-pipelined bf16 GEMM: C = A[M,K] @ Bt[N,K]^T * scale ------------
// 8 waves (2M x 4N), per-wave 128x64 output (8x4 frags of 16x16x32).
// LDS: 4-slot ring of BK=32 K-phases, [slot][A|B][256*32] = 128 KiB.
// Per phase: [4 B-frag ds_reads (slot p+1) | 1 STAGE (slot p+3)] -> counted vmcnt ->
//   barrier -> [8 A-frag ds_reads JIT + 32 MFMA, setprio1] -> barrier.
// B-frags register-double-buffered (BA/BB, x2 unroll). vmcnt: 8 steady / 4 @nt-3 / 0 tail.
// M, N multiples of 256 (gx%4==0, nwg%8==0); K multiple of 32, K/32 >= 4.
template <bool WF32, bool WB16, bool RELU, bool HAS_BIAS>
__global__ __launch_bounds__(512, 2) void k_gemm256(const unsigned short* __restrict__ A,
                                                    const unsigned short* __restrict__ Bt,
                                                    float* __restrict__ Cf,
                                                    unsigned short* __restrict__ Cb,
                                                    const float* __restrict__ bias,
                                                    int M, int N, int K,
                                                    long aBatch, long bBatch, long cBatch,
                                                    float scale) {
  __shared__ unsigned short lds[4][2][256 * 32];  // [slot][A|B] 128 KiB
  const int tid = threadIdx.x;
  const int lane = tid & 63;
  const int wid = tid >> 6;              // 0..7
  const int wr = wid >> 2, wc = wid & 3; // 2 x 4 wave grid

  // T1 + L2 locality: XCD gets a contiguous chunk of a (4-m-wide, n-fast) global order.
  const int gx = gridDim.x, gy = gridDim.y;
  const int nwg = gx * gy;
  const int id = blockIdx.y * gx + blockIdx.x;
  const int qq = nwg >> 3;
  const int s = (id & 7) * qq + (id >> 3);  // global order index
  const int g4 = s / (gy * 4);
  const int r4 = s - g4 * gy * 4;
  const int m0 = (g4 * 4 + (r4 & 3)) * 256;
  const int n0 = (r4 >> 2) * 256;
  const int z = blockIdx.z;
  A += (size_t)z * aBatch;
  Bt += (size_t)z * bBatch;

  // staging: per phase, per matrix, thread does 2 gload16 (A 256x32 = 16KB = 512thr*32B).
  // linear dest elem = j*4096 + tid*8 -> row = j*128 + tid/4, chunk_dst = tid&3.
  // source chunk = chunk_dst ^ (row&3)  (bank-balancing involution)
  const int srow = tid >> 2;
  const int csrc = (tid & 3) ^ (srow & 3);
  const unsigned short* ga0 = A + (size_t)(m0 + srow) * K + csrc * 8;
  const unsigned short* ga1 = A + (size_t)(m0 + 128 + srow) * K + csrc * 8;
  const unsigned short* gb0 = Bt + (size_t)(n0 + srow) * K + csrc * 8;
  const unsigned short* gb1 = Bt + (size_t)(n0 + 128 + srow) * K + csrc * 8;
  const int waveDst = (wid << 9);  // wave-uniform LDS elem offset; +lane*8 implicit

  auto STAGE = [&](int step) {
    const int slot = step & 3;
    const size_t ko = (size_t)step << 5;
    const unsigned short* la = &lds[slot][0][0];
    const unsigned short* lb = &lds[slot][1][0];
    gload16(ga0 + ko, la + waveDst);
    gload16(ga1 + ko, la + 4096 + waveDst);
    gload16(gb0 + ko, lb + waveDst);
    gload16(gb1 + ko, lb + 4096 + waveDst);
  };

  f32x4 acc[8][4] = {};
  const int fr = lane & 15;
  const int cc = ((lane >> 4) ^ (fr & 3)) * 8;  // swizzled chunk elem offset
  const int nt = K >> 5;

  auto RD_B = [&](int slot, s16x8* rb) {
    const unsigned short* lb = &lds[slot][1][0];
#pragma unroll
    for (int ni = 0; ni < 4; ++ni)
      rb[ni] = *(const s16x8*)(lb + ((wc * 64 + ni * 16 + fr) * 32 + cc));
  };
  auto PHASE_MM = [&](int slot, s16x8* rb) {
    const unsigned short* la = &lds[slot][0][0];
    __builtin_amdgcn_s_setprio(1);
    s16x8 ra[8];
#pragma unroll
    for (int mi = 0; mi < 8; ++mi)
      ra[mi] = *(const s16x8*)(la + ((wr * 128 + mi * 16 + fr) * 32 + cc));
#pragma unroll
    for (int mi = 0; mi < 8; ++mi)
#pragma unroll
      for (int ni = 0; ni < 4; ++ni)
        acc[mi][ni] = __builtin_amdgcn_mfma_f32_16x16x32_bf16(ra[mi], rb[ni], acc[mi][ni], 0, 0, 0);
    __builtin_amdgcn_s_setprio(0);
  };
  auto VMW = [&](int p) {  // counted vmcnt: guarantee slot p+1 landed for next phase's RD_B
    const int rem = nt - p;
    if (rem > 3)      asm volatile("s_waitcnt vmcnt(8)" ::: "memory");
    else if (rem == 3) asm volatile("s_waitcnt vmcnt(4)" ::: "memory");
    else               asm volatile("s_waitcnt vmcnt(0)" ::: "memory");
  };

  s16x8 BA[4], BB[4];

  STAGE(0); STAGE(1); STAGE(2);
  asm volatile("s_waitcnt vmcnt(4)" ::: "memory");  // slots 0,1 landed
  __builtin_amdgcn_s_barrier();
  asm volatile("" ::: "memory");
  RD_B(0, BA);

  for (int t = 0; t < nt; t += 2) {
    // phase t (even): MFMA from BA(slot t); preload BB from slot t+1
    RD_B((t + 1) & 3, BB);
    if (t + 3 < nt) STAGE(t + 3);
    VMW(t);
    __builtin_amdgcn_s_barrier();
    asm volatile("" ::: "memory");
    PHASE_MM(t & 3, BA);
    asm volatile("" ::: "memory");
    __builtin_amdgcn_s_barrier();
    // phase t+1 (odd): MFMA from BB(slot t+1); preload BA from slot t+2
    if (t + 2 < nt) RD_B((t + 2) & 3, BA);
    if (t + 4 < nt) STAGE(t + 4);
    VMW(t + 1);
    __builtin_amdgcn_s_barrier();
    asm volatile("" ::: "memory");
    PHASE_MM((t + 1) & 3, BB);
    asm volatile("" ::: "memory");
    __builtin_amdgcn_s_barrier();
  }

  // epilogue: D mapping col=lane&15, row=(lane>>4)*4+reg  [verified m89]
  const int er = lane & 15, eq = lane >> 4;
#pragma unroll
  for (int mi = 0; mi < 8; ++mi) {
#pragma unroll
    for (int ni = 0; ni < 4; ++ni) {
#pragma unroll
      for (int r = 0; r < 4; ++r) {
        int row = m0 + wr * 128 + mi * 16 + eq * 4 + r;
        int col = n0 + wc * 64 + ni * 16 + er;
        float v = acc[mi][ni][r] * scale;
        if (HAS_BIAS) v += bias[col];
        if (RELU) v = v > 0.f ? v : 0.f;
        size_t idx = (size_t)z * cBatch + (size_t)row * N + col;
        if (WF32) Cf[idx] = v;
        if (WB16) Cb[idx] = f2bf(v);
      }
    }
  }
}

// ---------------- row softmax, IN PLACE on bf16 scores [rows][2048] ----------------
__global__ __launch_bounds__(256) void k_softmax(unsigned short* __restrict__ sa) {
  __shared__ float red[4];
  const int row = blockIdx.x;
  const int tid = threadIdx.x;
  unsigned short* sr = sa + (size_t)row * Ss;
  ushort4 u0 = ((const ushort4*)sr)[tid];
  ushort4 u1 = ((const ushort4*)sr)[tid + 256];
  float e[8];
  e[0] = bf2f(u0.x); e[1] = bf2f(u0.y); e[2] = bf2f(u0.z); e[3] = bf2f(u0.w);
  e[4] = bf2f(u1.x); e[5] = bf2f(u1.y); e[6] = bf2f(u1.z); e[7] = bf2f(u1.w);
  float m = fmaxf(fmaxf(fmaxf(e[0], e[1]), fmaxf(e[2], e[3])),
                  fmaxf(fmaxf(e[4], e[5]), fmaxf(e[6], e[7])));
  for (int s = 1; s < 64; s <<= 1) m = fmaxf(m, __shfl_xor(m, s, 64));
  if ((tid & 63) == 0) red[tid >> 6] = m;
  __syncthreads();
  m = fmaxf(fmaxf(red[0], red[1]), fmaxf(red[2], red[3]));
  __syncthreads();
  float sum = 0.f;
#pragma unroll
  for (int j = 0; j < 8; ++j) { e[j] = __expf(e[j] - m); sum += e[j]; }
  for (int s = 1; s < 64; s <<= 1) sum += __shfl_xor(sum, s, 64);
  if ((tid & 63) == 0) red[tid >> 6] = sum;
  __syncthreads();
  sum = red[0] + red[1] + red[2] + red[3];
  float inv = 1.f / sum;
  ushort4 o0, o1;
  o0.x = f2bf(e[0] * inv); o0.y = f2bf(e[1] * inv);
  o0.z = f2bf(e[2] * inv); o0.w = f2bf(e[3] * inv);
  o1.x = f2bf(e[4] * inv); o1.y = f2bf(e[5] * inv);
  o1.z = f2bf(e[6] * inv); o1.w = f2bf(e[7] * inv);
  ((ushort4*)sr)[tid] = o0;
  ((ushort4*)sr)[tid + 256] = o1;
}

// ---------------- residual + LayerNorm ----------------
template <bool A_F32, bool OUT_F32>
__global__ __launch_bounds__(256) void k_ln(const void* __restrict__ a,
                                            const unsigned short* __restrict__ bb,
                                            const float* __restrict__ gamma,
                                            const float* __restrict__ beta,
                                            void* __restrict__ outp) {
  __shared__ float red[4];
  const int row = blockIdx.x;
  const int tid = threadIdx.x;
  float v[4];
  if (A_F32) {
    float4 av = ((const float4*)((const float*)a + (size_t)row * Ee))[tid];
    v[0] = av.x; v[1] = av.y; v[2] = av.z; v[3] = av.w;
  } else {
    ushort4 av = ((const ushort4*)((const unsigned short*)a + (size_t)row * Ee))[tid];
    v[0] = bf2f(av.x); v[1] = bf2f(av.y); v[2] = bf2f(av.z); v[3] = bf2f(av.w);
  }
  ushort4 bv = ((const ushort4*)(bb + (size_t)row * Ee))[tid];
  v[0] += bf2f(bv.x); v[1] += bf2f(bv.y); v[2] += bf2f(bv.z); v[3] += bf2f(bv.w);
  float s = v[0] + v[1] + v[2] + v[3];
  float q = v[0] * v[0] + v[1] * v[1] + v[2] * v[2] + v[3] * v[3];
  for (int sh = 1; sh < 64; sh <<= 1) {
    s += __shfl_xor(s, sh, 64);
    q += __shfl_xor(q, sh, 64);
  }
  if ((tid & 63) == 0) red[tid >> 6] = s;
  __syncthreads();
  s = red[0] + red[1] + red[2] + red[3];
  __syncthreads();
  if ((tid & 63) == 0) red[tid >> 6] = q;
  __syncthreads();
  q = red[0] + red[1] + red[2] + red[3];
  float mu = s * (1.f / Ee);
  float var = q * (1.f / Ee) - mu * mu;
  float rinv = rsqrtf(var + 1e-5f);
  int c = tid * 4;
  float o0 = (v[0] - mu) * rinv * gamma[c + 0] + beta[c + 0];
  float o1 = (v[1] - mu) * rinv * gamma[c + 1] + beta[c + 1];
  float o2 = (v[2] - mu) * rinv * gamma[c + 2] + beta[c + 2];
  float o3 = (v[3] - mu) * rinv * gamma[c + 3] + beta[c + 3];
  if (OUT_F32) {
    float4 o; o.x = o0; o.y = o1; o.z = o2; o.w = o3;
    ((float4*)((float*)outp + (size_t)row * Ee))[tid] = o;
  } else {
    ushort4 o;
    o.x = f2bf(o0); o.y = f2bf(o1); o.z = f2bf(o2); o.w = f2bf(o3);
    ((ushort4*)((unsigned short*)outp + (size_t)row * Ee))[tid] = o;
  }
}

extern "C" void kernel_launch(void* const* d_in, const int* in_sizes, int n_in,
                              void* d_out, int out_size, void* d_ws, size_t ws_size,
                              hipStream_t stream) {
  const float* x = (const float*)d_in[0];
  const float* Wq = (const float*)d_in[1];
  const float* bq = (const float*)d_in[2];
  const float* Wk = (const float*)d_in[3];
  const float* bk = (const float*)d_in[4];
  const float* Wv = (const float*)d_in[5];
  const float* bv = (const float*)d_in[6];
  const float* g1 = (const float*)d_in[7];
  const float* be1 = (const float*)d_in[8];
  const float* W1 = (const float*)d_in[9];
  const float* b1 = (const float*)d_in[10];
  const float* W2 = (const float*)d_in[11];
  const float* b2 = (const float*)d_in[12];
  const float* g2 = (const float*)d_in[13];
  const float* be2 = (const float*)d_in[14];

  float* out = (float*)d_out;          // return order: (out, k, q, v), all f32
  float* kO = out + OUT_SLOT;
  float* qO = out + 2 * OUT_SLOT;
  float* vO = out + 3 * OUT_SLOT;

  char* ws = (char*)d_ws;
  unsigned short* xb  = (unsigned short*)(ws + 0);             // 33.6 MB
  unsigned short* WqT = (unsigned short*)(ws + 33554432ull);   // 2 MB
  unsigned short* WkT = (unsigned short*)(ws + 35651584ull);   // 2 MB
  unsigned short* WvT = (unsigned short*)(ws + 37748736ull);   // 2 MB
  unsigned short* W1T = (unsigned short*)(ws + 39845888ull);   // 8.4 MB  [F][E]
  unsigned short* W2T = (unsigned short*)(ws + 48234496ull);   // 8.4 MB  [E][F]
  unsigned short* qb  = (unsigned short*)(ws + 56623104ull);   // 33.6 MB bf16 q
  unsigned short* kb  = (unsigned short*)(ws + 90177536ull);   // 33.6 MB bf16 k
  unsigned short* vb  = (unsigned short*)(ws + 123731968ull);  // 33.6 MB bf16 v
  unsigned short* scb = (unsigned short*)(ws + 157286400ull);  // 67.1 MB bf16 scores/attn (in-place)
  unsigned short* vT  = (unsigned short*)(ws + 224395264ull);  // 33.6 MB
  unsigned short* ao  = (unsigned short*)(ws + 56623104ull);   // reuse qb (dead after scores)
  unsigned short* hb  = (unsigned short*)(ws + 90177536ull);   // reuse kb (dead after scores)
  unsigned short* f1b = (unsigned short*)(ws + 157286400ull);  // 134.2 MB reuse scb+vT (dead)
  unsigned short* f2b = (unsigned short*)(ws + 123731968ull);  // reuse vb (dead after transpose)

  dim3 tb(32, 8);
  // stage 0: conversions
  k_cvt_f32_bf16<<<2048, 256, 0, stream>>>(x, xb, M_TOK * Ee / 4);
  k_transpose_w<<<dim3(32, 32), tb, 0, stream>>>(Wq, WqT, Ee, Ee);
  k_transpose_w<<<dim3(32, 32), tb, 0, stream>>>(Wk, WkT, Ee, Ee);
  k_transpose_w<<<dim3(32, 32), tb, 0, stream>>>(Wv, WvT, Ee, Ee);
  k_transpose_w<<<dim3(128, 32), tb, 0, stream>>>(W1, W1T, Ee, Ff);
  k_transpose_w<<<dim3(32, 128), tb, 0, stream>>>(W2, W2T, Ff, Ee);
  // stage 1: q,k,v  (dual write: f32 -> d_out slot, bf16 -> ws)
  k_gemm256<true, true, false, true><<<dim3(64, 4, 1), 512, 0, stream>>>(
      xb, WqT, qO, qb, bq, M_TOK, Ee, Ee, 0, 0, 0, 1.f);
  k_gemm256<true, true, false, true><<<dim3(64, 4, 1), 512, 0, stream>>>(
      xb, WkT, kO, kb, bk, M_TOK, Ee, Ee, 0, 0, 0, 1.f);
  k_gemm256<true, true, false, true><<<dim3(64, 4, 1), 512, 0, stream>>>(
      xb, WvT, vO, vb, bv, M_TOK, Ee, Ee, 0, 0, 0, 1.f);
  // stage 2: scores = q @ k^T / 32  (batched over 8) -> bf16
  k_gemm256<false, true, false, false><<<dim3(8, 8, 8), 512, 0, stream>>>(
      qb, kb, nullptr, scb, nullptr, Ss, Ss, Ee, (long)Ss * Ee, (long)Ss * Ee, (long)Ss * Ss,
      0.03125f);
  // stage 3: softmax rows, in place
  k_softmax<<<Bb * Ss, 256, 0, stream>>>(scb);
  // stage 4: vT then attn @ v
  k_transpose_v<<<dim3(32, 64, 8), tb, 0, stream>>>(vb, vT);
  k_gemm256<false, true, false, false><<<dim3(8, 4, 8), 512, 0, stream>>>(
      scb, vT, nullptr, ao, nullptr, Ss, Ee, Ss, (long)Ss * Ss, (long)Ee * Ss, (long)Ss * Ee, 1.f);
  // stage 5: LN1 -> h (bf16)
  k_ln<true, false><<<M_TOK, 256, 0, stream>>>(x, ao, g1, be1, hb);
  // stage 6: FFN
  k_gemm256<false, true, true, true><<<dim3(64, 16, 1), 512, 0, stream>>>(
      hb, W1T, nullptr, f1b, b1, M_TOK, Ff, Ee, 0, 0, 0, 1.f);
  k_gemm256<false, true, false, true><<<dim3(64, 4, 1), 512, 0, stream>>>(
      f1b, W2T, nullptr, f2b, b2, M_TOK, Ee, Ff, 0, 0, 0, 1.f);
  // stage 7: LN2 -> out (f32)
  k_ln<false, true><<<M_TOK, 256, 0, stream>>>(hb, f2b, g2, be2, out);
}

// Round 6
// 692.727 us; speedup vs baseline: 1.5298x; 1.0617x over previous
//
#include <hip/hip_runtime.h>
#include <hip/hip_bf16.h>
#include <stdint.h>

typedef __attribute__((ext_vector_type(8))) short s16x8;
typedef __attribute__((ext_vector_type(4))) float f32x4;

static constexpr int Bb = 8, Ss = 2048, Ee = 1024, Ff = 4096;
static constexpr int M_TOK = Bb * Ss;                      // 16384
static constexpr size_t OUT_SLOT = (size_t)M_TOK * Ee;     // elements per output tensor

__device__ inline unsigned short f2bf(float f) {
  unsigned int u = __float_as_uint(f);
  unsigned int r = (u + 0x7FFFu + ((u >> 16) & 1u)) >> 16;
  return (unsigned short)r;
}
__device__ inline float bf2f(unsigned short h) {
  return __uint_as_float(((unsigned int)h) << 16);
}

// direct HBM -> LDS, 16B per lane; lds dest = wave-uniform base + lane*16
__device__ inline void gload16(const unsigned short* g, const unsigned short* l) {
  __builtin_amdgcn_global_load_lds(
      (const __attribute__((address_space(1))) void*)g,
      (__attribute__((address_space(3))) void*)(unsigned short*)l, 16, 0, 0);
}

// ---------------- elementwise f32 -> bf16 ----------------
__global__ __launch_bounds__(256) void k_cvt_f32_bf16(const float* __restrict__ in,
                                                      unsigned short* __restrict__ out, int n4) {
  int i = blockIdx.x * blockDim.x + threadIdx.x;
  int stride = gridDim.x * blockDim.x;
  for (; i < n4; i += stride) {
    float4 v = ((const float4*)in)[i];
    ushort4 o;
    o.x = f2bf(v.x); o.y = f2bf(v.y); o.z = f2bf(v.z); o.w = f2bf(v.w);
    ((ushort4*)out)[i] = o;
  }
}

// ---------------- concat 3 bias vectors [1024] -> [3072] ----------------
__global__ __launch_bounds__(256) void k_concat3(const float* __restrict__ a,
                                                 const float* __restrict__ b,
                                                 const float* __restrict__ c,
                                                 float* __restrict__ out) {
  int i = blockIdx.x * 256 + threadIdx.x;  // grid 12 x 256 = 3072
  const float* src = (i < 1024) ? a : (i < 2048) ? b : c;
  out[i] = src[i & 1023];
}

// ---------------- transpose+convert W[R][C] f32 -> WT[C][R] bf16 ----------------
__global__ __launch_bounds__(256) void k_transpose_w(const float* __restrict__ in,
                                                     unsigned short* __restrict__ out,
                                                     int R, int C) {
  __shared__ float t[32][33];
  int c0 = blockIdx.x * 32, r0 = blockIdx.y * 32;
  int tx = threadIdx.x, ty = threadIdx.y;
  for (int i = ty; i < 32; i += 8)
    t[i][tx] = in[(size_t)(r0 + i) * C + c0 + tx];
  __syncthreads();
  for (int i = ty; i < 32; i += 8)
    out[(size_t)(c0 + i) * R + r0 + tx] = f2bf(t[tx][i]);
}

// ---------------- per-batch transpose v[S][E] bf16 -> vT[E][S] bf16 ----------------
__global__ __launch_bounds__(256) void k_transpose_v(const unsigned short* __restrict__ v,
                                                     unsigned short* __restrict__ vT) {
  __shared__ unsigned short t[32][33];
  int b = blockIdx.z;
  const unsigned short* in = v + (size_t)b * Ss * Ee;
  unsigned short* out = vT + (size_t)b * Ee * Ss;
  int c0 = blockIdx.x * 32, r0 = blockIdx.y * 32;  // c over E, r over S
  int tx = threadIdx.x, ty = threadIdx.y;
  for (int i = ty; i < 32; i += 8)
    t[i][tx] = in[(size_t)(r0 + i) * Ee + c0 + tx];
  __syncthreads();
  for (int i = ty; i < 32; i += 8)
    out[(size_t)(c0 + i) * Ss + r0 + tx] = t[tx][i];
}

// ---------------- 256x256 sub-phase-pipelined bf16 GEMM: C = A @ Bt^T * scale ----------------
// 8 waves (2M x 4N), per-wave 128x64 output. LDS: 4-slot ring of BK=32 tiles (128 KiB).
// Per tile t, 2 sub-phases of 16 MFMAs:
//  sub0: [4 B-reads + 4 A-reads (slot t) | STAGE_A(t+3)] -> vmcnt(6|4|0) -> bar -> MFMA mi0-3 -> bar
//  sub1: [4 A-reads (slot t)             | STAGE_B(t+3)]                 -> bar -> MFMA mi4-7 -> bar
// Slot t's landing is proven by tile t-1's vmcnt(6) (one full tile ahead) -> no read race.
// Swizzle: element (r, chunk c) stored at phys chunk c ^ ((r>>1)&3) -> 2-way-max bank aliasing.
// QKV mode: N=3072 fused q|k|v; epilogue demuxes by col>>10 (Cf = d_out base, Cb = qb base).
// M,N multiples of 256 (nwg%8==0); K multiple of 32, K/32 >= 4.
template <bool QKV, bool WF32, bool WB16, bool RELU, bool HAS_BIAS>
__global__ __launch_bounds__(512, 2) void k_gemm256(const unsigned short* __restrict__ A,
                                                    const unsigned short* __restrict__ Bt,
                                                    float* __restrict__ Cf,
                                                    unsigned short* __restrict__ Cb,
                                                    const float* __restrict__ bias,
                                                    int M, int N, int K,
                                                    long aBatch, long bBatch, long cBatch,
                                                    float scale) {
  __shared__ unsigned short lds[4][2][256 * 32];  // [slot][A|B] 128 KiB
  const int tid = threadIdx.x;
  const int lane = tid & 63;
  const int wid = tid >> 6;              // 0..7
  const int wr = wid >> 2, wc = wid & 3; // 2 x 4 wave grid

  // T1 + L2 locality: XCD gets a contiguous chunk of a (4-m-wide, n-fast) global order.
  const int gx = gridDim.x, gy = gridDim.y;
  const int nwg = gx * gy;
  const int id = blockIdx.y * gx + blockIdx.x;
  const int qq = nwg >> 3;
  const int s = (id & 7) * qq + (id >> 3);  // global order index
  const int g4 = s / (gy * 4);
  const int r4 = s - g4 * gy * 4;
  const int m0 = (g4 * 4 + (r4 & 3)) * 256;
  const int n0 = (r4 >> 2) * 256;
  const int z = blockIdx.z;
  A += (size_t)z * aBatch;
  Bt += (size_t)z * bBatch;

  // staging: dest elem = j*4096 + tid*8 -> row = j*128 + tid/4, chunk_dst = tid&3.
  // source chunk = chunk_dst ^ ((row>>1)&3); row>>1&3 == (tid>>3)&3 for both j (128 = 0 mod 8).
  const int srow = tid >> 2;
  const int csrc = (tid & 3) ^ ((tid >> 3) & 3);
  const unsigned short* ga0 = A + (size_t)(m0 + srow) * K + csrc * 8;
  const unsigned short* ga1 = A + (size_t)(m0 + 128 + srow) * K + csrc * 8;
  const unsigned short* gb0 = Bt + (size_t)(n0 + srow) * K + csrc * 8;
  const unsigned short* gb1 = Bt + (size_t)(n0 + 128 + srow) * K + csrc * 8;
  const int waveDst = (wid << 9);  // wave-uniform LDS elem offset; +lane*8 implicit

  auto STAGE_A = [&](int step) {
    const int slot = step & 3;
    const size_t ko = (size_t)step << 5;
    const unsigned short* la = &lds[slot][0][0];
    gload16(ga0 + ko, la + waveDst);
    gload16(ga1 + ko, la + 4096 + waveDst);
  };
  auto STAGE_B = [&](int step) {
    const int slot = step & 3;
    const size_t ko = (size_t)step << 5;
    const unsigned short* lb = &lds[slot][1][0];
    gload16(gb0 + ko, lb + waveDst);
    gload16(gb1 + ko, lb + 4096 + waveDst);
  };

  f32x4 acc[8][4] = {};
  const int fr = lane & 15;
  const int cc = ((lane >> 4) ^ ((fr >> 1) & 3)) * 8;  // swizzled chunk elem offset
  const int nt = K >> 5;

  // prologue: stage tiles 0,1,2; wait tile 0 (oldest 4 of 12)
  STAGE_A(0); STAGE_B(0); STAGE_A(1); STAGE_B(1); STAGE_A(2); STAGE_B(2);
  asm volatile("s_waitcnt vmcnt(8)" ::: "memory");
  __builtin_amdgcn_s_barrier();
  asm volatile("" ::: "memory");

  for (int t = 0; t < nt; ++t) {
    const int slot = t & 3;
    const unsigned short* la = &lds[slot][0][0];
    const unsigned short* lb = &lds[slot][1][0];
    s16x8 ra[4], rb[4];
    // ---- sub-phase 0: B all + A half0, stage A(t+3), vmcnt once per tile ----
#pragma unroll
    for (int ni = 0; ni < 4; ++ni)
      rb[ni] = *(const s16x8*)(lb + ((wc * 64 + ni * 16 + fr) * 32 + cc));
#pragma unroll
    for (int mi = 0; mi < 4; ++mi)
      ra[mi] = *(const s16x8*)(la + ((wr * 128 + mi * 16 + fr) * 32 + cc));
    if (t + 3 < nt) {
      STAGE_A(t + 3);
      asm volatile("s_waitcnt vmcnt(6)" ::: "memory");   // tile t+1 fully landed
    } else if (t + 2 < nt) {
      asm volatile("s_waitcnt vmcnt(4)" ::: "memory");
    } else {
      asm volatile("s_waitcnt vmcnt(0)" ::: "memory");
    }
    __builtin_amdgcn_s_barrier();
    asm volatile("" ::: "memory");
    __builtin_amdgcn_s_setprio(1);
#pragma unroll
    for (int mi = 0; mi < 4; ++mi)
#pragma unroll
      for (int ni = 0; ni < 4; ++ni)
        acc[mi][ni] = __builtin_amdgcn_mfma_f32_16x16x32_bf16(ra[mi], rb[ni], acc[mi][ni], 0, 0, 0);
    __builtin_amdgcn_s_setprio(0);
    asm volatile("" ::: "memory");
    __builtin_amdgcn_s_barrier();
    // ---- sub-phase 1: A half1, stage B(t+3) ----
#pragma unroll
    for (int mi = 0; mi < 4; ++mi)
      ra[mi] = *(const s16x8*)(la + ((wr * 128 + (mi + 4) * 16 + fr) * 32 + cc));
    if (t + 3 < nt) STAGE_B(t + 3);
    __builtin_amdgcn_s_barrier();
    asm volatile("" ::: "memory");
    __builtin_amdgcn_s_setprio(1);
#pragma unroll
    for (int mi = 0; mi < 4; ++mi)
#pragma unroll
      for (int ni = 0; ni < 4; ++ni)
        acc[mi + 4][ni] = __builtin_amdgcn_mfma_f32_16x16x32_bf16(ra[mi], rb[ni], acc[mi + 4][ni], 0, 0, 0);
    __builtin_amdgcn_s_setprio(0);
    asm volatile("" ::: "memory");
    __builtin_amdgcn_s_barrier();
  }

  // epilogue: D mapping col=lane&15, row=(lane>>4)*4+reg  [verified m89]
  const int er = lane & 15, eq = lane >> 4;
#pragma unroll
  for (int mi = 0; mi < 8; ++mi) {
#pragma unroll
    for (int ni = 0; ni < 4; ++ni) {
#pragma unroll
      for (int r = 0; r < 4; ++r) {
        int row = m0 + wr * 128 + mi * 16 + eq * 4 + r;
        int col = n0 + wc * 64 + ni * 16 + er;
        float v = acc[mi][ni][r] * scale;
        if (HAS_BIAS) v += bias[col];
        if (RELU) v = v > 0.f ? v : 0.f;
        if (QKV) {
          int which = col >> 10;       // 0=q, 1=k, 2=v
          int c2 = col & 1023;
          size_t ro = (size_t)row * 1024 + c2;
          int fslot = (which == 0) ? 2 : (which == 1) ? 1 : 3;  // d_out order: out,k,q,v
          Cf[(size_t)fslot * OUT_SLOT + ro] = v;
          Cb[(size_t)which * OUT_SLOT + ro] = f2bf(v);          // ws order: q,k,v
        } else {
          size_t idx = (size_t)z * cBatch + (size_t)row * N + col;
          if (WF32) Cf[idx] = v;
          if (WB16) Cb[idx] = f2bf(v);
        }
      }
    }
  }
}

// ---------------- row softmax, IN PLACE on bf16 scores [rows][2048] ----------------
__global__ __launch_bounds__(256) void k_softmax(unsigned short* __restrict__ sa) {
  __shared__ float red[4];
  const int row = blockIdx.x;
  const int tid = threadIdx.x;
  unsigned short* sr = sa + (size_t)row * Ss;
  ushort4 u0 = ((const ushort4*)sr)[tid];
  ushort4 u1 = ((const ushort4*)sr)[tid + 256];
  float e[8];
  e[0] = bf2f(u0.x); e[1] = bf2f(u0.y); e[2] = bf2f(u0.z); e[3] = bf2f(u0.w);
  e[4] = bf2f(u1.x); e[5] = bf2f(u1.y); e[6] = bf2f(u1.z); e[7] = bf2f(u1.w);
  float m = fmaxf(fmaxf(fmaxf(e[0], e[1]), fmaxf(e[2], e[3])),
                  fmaxf(fmaxf(e[4], e[5]), fmaxf(e[6], e[7])));
  for (int s = 1; s < 64; s <<= 1) m = fmaxf(m, __shfl_xor(m, s, 64));
  if ((tid & 63) == 0) red[tid >> 6] = m;
  __syncthreads();
  m = fmaxf(fmaxf(red[0], red[1]), fmaxf(red[2], red[3]));
  __syncthreads();
  float sum = 0.f;
#pragma unroll
  for (int j = 0; j < 8; ++j) { e[j] = __expf(e[j] - m); sum += e[j]; }
  for (int s = 1; s < 64; s <<= 1) sum += __shfl_xor(sum, s, 64);
  if ((tid & 63) == 0) red[tid >> 6] = sum;
  __syncthreads();
  sum = red[0] + red[1] + red[2] + red[3];
  float inv = 1.f / sum;
  ushort4 o0, o1;
  o0.x = f2bf(e[0] * inv); o0.y = f2bf(e[1] * inv);
  o0.z = f2bf(e[2] * inv); o0.w = f2bf(e[3] * inv);
  o1.x = f2bf(e[4] * inv); o1.y = f2bf(e[5] * inv);
  o1.z = f2bf(e[6] * inv); o1.w = f2bf(e[7] * inv);
  ((ushort4*)sr)[tid] = o0;
  ((ushort4*)sr)[tid + 256] = o1;
}

// ---------------- residual + LayerNorm ----------------
template <bool A_F32, bool OUT_F32>
__global__ __launch_bounds__(256) void k_ln(const void* __restrict__ a,
                                            const unsigned short* __restrict__ bb,
                                            const float* __restrict__ gamma,
                                            const float* __restrict__ beta,
                                            void* __restrict__ outp) {
  __shared__ float red[4];
  const int row = blockIdx.x;
  const int tid = threadIdx.x;
  float v[4];
  if (A_F32) {
    float4 av = ((const float4*)((const float*)a + (size_t)row * Ee))[tid];
    v[0] = av.x; v[1] = av.y; v[2] = av.z; v[3] = av.w;
  } else {
    ushort4 av = ((const ushort4*)((const unsigned short*)a + (size_t)row * Ee))[tid];
    v[0] = bf2f(av.x); v[1] = bf2f(av.y); v[2] = bf2f(av.z); v[3] = bf2f(av.w);
  }
  ushort4 bv = ((const ushort4*)(bb + (size_t)row * Ee))[tid];
  v[0] += bf2f(bv.x); v[1] += bf2f(bv.y); v[2] += bf2f(bv.z); v[3] += bf2f(bv.w);
  float s = v[0] + v[1] + v[2] + v[3];
  float q = v[0] * v[0] + v[1] * v[1] + v[2] * v[2] + v[3] * v[3];
  for (int sh = 1; sh < 64; sh <<= 1) {
    s += __shfl_xor(s, sh, 64);
    q += __shfl_xor(q, sh, 64);
  }
  if ((tid & 63) == 0) red[tid >> 6] = s;
  __syncthreads();
  s = red[0] + red[1] + red[2] + red[3];
  __syncthreads();
  if ((tid & 63) == 0) red[tid >> 6] = q;
  __syncthreads();
  q = red[0] + red[1] + red[2] + red[3];
  float mu = s * (1.f / Ee);
  float var = q * (1.f / Ee) - mu * mu;
  float rinv = rsqrtf(var + 1e-5f);
  int c = tid * 4;
  float o0 = (v[0] - mu) * rinv * gamma[c + 0] + beta[c + 0];
  float o1 = (v[1] - mu) * rinv * gamma[c + 1] + beta[c + 1];
  float o2 = (v[2] - mu) * rinv * gamma[c + 2] + beta[c + 2];
  float o3 = (v[3] - mu) * rinv * gamma[c + 3] + beta[c + 3];
  if (OUT_F32) {
    float4 o; o.x = o0; o.y = o1; o.z = o2; o.w = o3;
    ((float4*)((float*)outp + (size_t)row * Ee))[tid] = o;
  } else {
    ushort4 o;
    o.x = f2bf(o0); o.y = f2bf(o1); o.z = f2bf(o2); o.w = f2bf(o3);
    ((ushort4*)((unsigned short*)outp + (size_t)row * Ee))[tid] = o;
  }
}

extern "C" void kernel_launch(void* const* d_in, const int* in_sizes, int n_in,
                              void* d_out, int out_size, void* d_ws, size_t ws_size,
                              hipStream_t stream) {
  const float* x = (const float*)d_in[0];
  const float* Wq = (const float*)d_in[1];
  const float* bq = (const float*)d_in[2];
  const float* Wk = (const float*)d_in[3];
  const float* bk = (const float*)d_in[4];
  const float* Wv = (const float*)d_in[5];
  const float* bv = (const float*)d_in[6];
  const float* g1 = (const float*)d_in[7];
  const float* be1 = (const float*)d_in[8];
  const float* W1 = (const float*)d_in[9];
  const float* b1 = (const float*)d_in[10];
  const float* W2 = (const float*)d_in[11];
  const float* b2 = (const float*)d_in[12];
  const float* g2 = (const float*)d_in[13];
  const float* be2 = (const float*)d_in[14];

  float* out = (float*)d_out;          // return order: (out, k, q, v), all f32

  char* ws = (char*)d_ws;
  unsigned short* xb    = (unsigned short*)(ws + 0);             // 33.6 MB
  unsigned short* WqkvT = (unsigned short*)(ws + 33554432ull);   // 6.3 MB [3072][1024]
  unsigned short* W1T   = (unsigned short*)(ws + 39845888ull);   // 8.4 MB  [F][E]
  unsigned short* W2T   = (unsigned short*)(ws + 48234496ull);   // 8.4 MB  [E][F]
  unsigned short* qb    = (unsigned short*)(ws + 56623104ull);   // 33.6 MB bf16 q (k,v follow contig)
  unsigned short* kb    = (unsigned short*)(ws + 90177536ull);   // 33.6 MB bf16 k
  unsigned short* vb    = (unsigned short*)(ws + 123731968ull);  // 33.6 MB bf16 v
  unsigned short* scb   = (unsigned short*)(ws + 157286400ull);  // 67.1 MB bf16 scores/attn
  unsigned short* vT    = (unsigned short*)(ws + 224395264ull);  // 33.6 MB
  float*          bqkv  = (float*)(ws + 257949696ull);           // 12 KB
  unsigned short* ao    = (unsigned short*)(ws + 56623104ull);   // reuse qb (dead after scores)
  unsigned short* hb    = (unsigned short*)(ws + 90177536ull);   // reuse kb (dead after scores)
  unsigned short* f1b   = (unsigned short*)(ws + 157286400ull);  // reuse scb+vT (dead)
  unsigned short* f2b   = (unsigned short*)(ws + 123731968ull);  // reuse vb (dead after transpose)

  dim3 tb(32, 8);
  // stage 0: conversions
  k_cvt_f32_bf16<<<2048, 256, 0, stream>>>(x, xb, M_TOK * Ee / 4);
  k_transpose_w<<<dim3(32, 32), tb, 0, stream>>>(Wq, WqkvT, Ee, Ee);
  k_transpose_w<<<dim3(32, 32), tb, 0, stream>>>(Wk, WqkvT + 1048576, Ee, Ee);
  k_transpose_w<<<dim3(32, 32), tb, 0, stream>>>(Wv, WqkvT + 2097152, Ee, Ee);
  k_transpose_w<<<dim3(128, 32), tb, 0, stream>>>(W1, W1T, Ee, Ff);
  k_transpose_w<<<dim3(32, 128), tb, 0, stream>>>(W2, W2T, Ff, Ee);
  k_concat3<<<12, 256, 0, stream>>>(bq, bk, bv, bqkv);
  // stage 1: fused q|k|v  (f32 -> d_out slots, bf16 -> ws)
  k_gemm256<true, true, true, false, true><<<dim3(64, 12, 1), 512, 0, stream>>>(
      xb, WqkvT, out, qb, bqkv, M_TOK, 3072, Ee, 0, 0, 0, 1.f);
  // stage 2: scores = q @ k^T / 32  (batched over 8) -> bf16
  k_gemm256<false, false, true, false, false><<<dim3(8, 8, 8), 512, 0, stream>>>(
      qb, kb, nullptr, scb, nullptr, Ss, Ss, Ee, (long)Ss * Ee, (long)Ss * Ee, (long)Ss * Ss,
      0.03125f);
  // stage 3: softmax rows, in place
  k_softmax<<<Bb * Ss, 256, 0, stream>>>(scb);
  // stage 4: vT then attn @ v
  k_transpose_v<<<dim3(32, 64, 8), tb, 0, stream>>>(vb, vT);
  k_gemm256<false, false, true, false, false><<<dim3(8, 4, 8), 512, 0, stream>>>(
      scb, vT, nullptr, ao, nullptr, Ss, Ee, Ss, (long)Ss * Ss, (long)Ee * Ss, (long)Ss * Ee, 1.f);
  // stage 5: LN1 -> h (bf16)
  k_ln<true, false><<<M_TOK, 256, 0, stream>>>(x, ao, g1, be1, hb);
  // stage 6: FFN
  k_gemm256<false, false, true, true, true><<<dim3(64, 16, 1), 512, 0, stream>>>(
      hb, W1T, nullptr, f1b, b1, M_TOK, Ff, Ee, 0, 0, 0, 1.f);
  k_gemm256<false, false, true, false, true><<<dim3(64, 4, 1), 512, 0, stream>>>(
      f1b, W2T, nullptr, f2b, b2, M_TOK, Ee, Ff, 0, 0, 0, 1.f);
  // stage 7: LN2 -> out (f32)
  k_ln<false, true><<<M_TOK, 256, 0, stream>>>(hb, f2b, g2, be2, out);
}